// Round 8
// baseline (398.896 us; speedup 1.0000x reference)
//
#include <hip/hip_runtime.h>
#include <hip/hip_bf16.h>
#include <float.h>

#define N_NODES 65536
#define S_SUP   2048
#define D_INF   32
#define HDIM    256
#define KNN     32
#define NBINS   4096
#define CAP     4096

// ---------------- node embedding: x = feat@projW + projb + sincos(pos) ----------------
__global__ void embed_kernel(const float* __restrict__ feat, const float* __restrict__ pos,
                             const float* __restrict__ W, const float* __restrict__ b,
                             float* __restrict__ x) {
    __shared__ float sf[64][32];    // feat tile
    __shared__ float sw[32][256];   // full proj_W
    __shared__ float sp[64];
    int tid = threadIdx.x;
    int rb = blockIdx.x * 64;
    for (int i = 0; i < 32; ++i) sw[i][tid] = W[i * 256 + tid];
    {
        int r = tid >> 2, kg = tid & 3;
        const float* src = feat + (size_t)(rb + r) * 32 + kg * 8;
        float4 v0 = *(const float4*)(src);
        float4 v1 = *(const float4*)(src + 4);
        *(float4*)&sf[r][kg * 8]     = v0;
        *(float4*)&sf[r][kg * 8 + 4] = v1;
    }
    if (tid < 64) sp[tid] = pos[rb + tid];
    __syncthreads();
    int c = tid;
    float wcol[32];
#pragma unroll
    for (int k = 0; k < 32; ++k) wcol[k] = sw[k][c];
    float bias = b[c];
    const float coef = -logf(10000.0f) / 127.0f;
    float fr = expf((float)(c & 127) * coef);
    bool is_sin = (c < 128);
    for (int r = 0; r < 64; ++r) {
        float acc = bias;
#pragma unroll
        for (int k = 0; k < 32; ++k) acc = fmaf(sf[r][k], wcol[k], acc);
        float e = sp[r] * fr;
        acc += is_sin ? sinf(e) : cosf(e);
        x[(size_t)(rb + r) * 256 + c] = acc;
    }
}

// ---------------- binning (counting sort by position) ----------------
__device__ __forceinline__ int pos_bin(float p) {
    int b = (int)(p * (float)NBINS);
    return min(max(b, 0), NBINS - 1);
}

__global__ void hist_kernel(const float* __restrict__ pos, int* __restrict__ bin_cnt) {
    int n = blockIdx.x * blockDim.x + threadIdx.x;
    atomicAdd(&bin_cnt[pos_bin(pos[n])], 1);
}

__global__ void scan_kernel(const int* __restrict__ bin_cnt, int* __restrict__ bin_ofs,
                            int* __restrict__ cursor) {
    __shared__ int sdata[1024];
    int t = threadIdx.x;
    int v[4]; int s = 0;
#pragma unroll
    for (int i = 0; i < 4; ++i) { v[i] = bin_cnt[t * 4 + i]; s += v[i]; }
    sdata[t] = s;
    __syncthreads();
    for (int off = 1; off < 1024; off <<= 1) {
        int add = (t >= off) ? sdata[t - off] : 0;
        __syncthreads();
        sdata[t] += add;
        __syncthreads();
    }
    int run = sdata[t] - s;   // exclusive prefix
#pragma unroll
    for (int i = 0; i < 4; ++i) {
        bin_ofs[t * 4 + i] = run;
        cursor[t * 4 + i]  = run;
        run += v[i];
    }
    if (t == 1023) bin_ofs[NBINS] = run;
}

__global__ void scatter_kernel(const float* __restrict__ pos, int* __restrict__ cursor,
                               int* __restrict__ sidx, float* __restrict__ spos) {
    int n = blockIdx.x * blockDim.x + threadIdx.x;
    float p = pos[n];
    int b = pos_bin(p);
    int dst = atomicAdd(&cursor[b], 1);
    sidx[dst] = n;
    spos[dst] = p;
}

// ---------------- exact top-32 nearest per supernode (1 wave / supernode) ----------------
__global__ void topk_kernel(const float* __restrict__ pos, const int* __restrict__ sup,
                            const int* __restrict__ bin_ofs, const int* __restrict__ sidx,
                            const float* __restrict__ spos,
                            int* __restrict__ nbr, int* __restrict__ within,
                            int* __restrict__ ncnt) {
    __shared__ float cd2[CAP];
    __shared__ int   cidx[CAP];
    __shared__ float rd2[KNN];
    __shared__ int   ridx[KNN];
    int s = blockIdx.x;
    int lane = threadIdx.x;
    float p = pos[sup[s]];
    int hb = pos_bin(p);
    const float BINW = 1.0f / (float)NBINS;
    int ccnt = 0;
    for (int r = 2;; r <<= 1) {
        int lo = max(hb - r, 0), hi = min(hb + r, NBINS - 1);
        int start = bin_ofs[lo], end = bin_ofs[hi + 1];
        ccnt = min(end - start, CAP);
        for (int i = lane; i < ccnt; i += 64) {
            float pp = spos[start + i];
            float d = p - pp;
            cd2[i] = d * d;
            cidx[i] = sidx[start + i];
        }
        __syncthreads();
        // any node NOT collected is at distance >= g from p (0.999 shrink guards binning fp rounding)
        float gl = (lo == 0) ? FLT_MAX : (p - (float)lo * BINW);
        float gr = (hi == NBINS - 1) ? FLT_MAX : ((float)(hi + 1) * BINW - p);
        float g = fminf(gl, gr);
        float g2 = (g >= FLT_MAX) ? FLT_MAX : (g * 0.999f) * (g * 0.999f);
        int cw = 0;
        for (int i = lane; i < ccnt; i += 64) cw += (cd2[i] < g2) ? 1 : 0;
        for (int o = 32; o; o >>= 1) cw += __shfl_xor(cw, o);
        if (cw >= KNN || (lo == 0 && hi == NBINS - 1)) break;
        __syncthreads();
    }
    // 32 exact argmin iterations on key (d2_bits, idx) — matches lax.top_k tie-breaking
    for (int t = 0; t < KNN; ++t) {
        unsigned long long best = ~0ULL;
        int bslot = -1;
        for (int i = lane; i < ccnt; i += 64) {
            unsigned long long k =
                ((unsigned long long)__float_as_uint(cd2[i]) << 32) | (unsigned)cidx[i];
            if (k < best) { best = k; bslot = i; }
        }
        unsigned long long mybest = best;
        for (int o = 32; o; o >>= 1) {
            unsigned long long other = __shfl_xor(best, o);
            best = best < other ? best : other;
        }
        if (mybest == best && bslot >= 0) cd2[bslot] = FLT_MAX;  // unique key -> one owner
        if (lane == 0) {
            rd2[t]  = __uint_as_float((unsigned)(best >> 32));
            ridx[t] = (int)(unsigned)(best & 0xffffffffULL);
        }
        __syncthreads();
    }
    const float R2 = (float)(0.005 * 0.005);
    if (lane < KNN) {
        float d2v = rd2[lane];
        int w = (d2v <= R2) ? 1 : 0;
        nbr[s * KNN + lane] = ridx[lane];
        within[s * KNN + lane] = w;
        unsigned long long m = __ballot(w != 0);
        int cnt = __popcll(m & 0xffffffffULL);
        if (lane == 0) ncnt[s] = cnt;
    }
}

// ---- generic f32 GEMM: C[M x ncols] = A(gather)[M x 256] @ B[256 x ncols-slab] (+ rowscale*bias), ldc-strided ----
__global__ void gemm64_kernel(const float* __restrict__ A, const int* __restrict__ rowidx,
                              const float* __restrict__ B, const float* __restrict__ bias,
                              const int* __restrict__ ncnt, float* __restrict__ C, int ldc) {
    __shared__ float At[32][68];   // [k][r], pad 68 keeps float4 alignment, reads are broadcast
    __shared__ float Bs[32][64];
    int tid = threadIdx.x;
    int rb = blockIdx.x * 64, cb = blockIdx.y * 64;
    int tx = tid & 15, ty = tid >> 4;
    float acc[4][4] = {};
    int lr = tid >> 2, kg = tid & 3;
    int arow = rowidx ? rowidx[rb + lr] : (rb + lr);
    const float* aptr = A + (size_t)arow * 256 + kg * 8;
    int k2 = tid >> 3, cg = tid & 7;
    const float* bptr = B + (size_t)k2 * 256 + cb + cg * 8;
    for (int kc = 0; kc < 256; kc += 32) {
        float4 a0 = *(const float4*)(aptr + kc);
        float4 a1 = *(const float4*)(aptr + kc + 4);
        float4 b0 = *(const float4*)(bptr + (size_t)kc * 256);
        float4 b1v = *(const float4*)(bptr + (size_t)kc * 256 + 4);
        At[kg * 8 + 0][lr] = a0.x; At[kg * 8 + 1][lr] = a0.y;
        At[kg * 8 + 2][lr] = a0.z; At[kg * 8 + 3][lr] = a0.w;
        At[kg * 8 + 4][lr] = a1.x; At[kg * 8 + 5][lr] = a1.y;
        At[kg * 8 + 6][lr] = a1.z; At[kg * 8 + 7][lr] = a1.w;
        *(float4*)&Bs[k2][cg * 8]     = b0;
        *(float4*)&Bs[k2][cg * 8 + 4] = b1v;
        __syncthreads();
#pragma unroll
        for (int k = 0; k < 32; ++k) {
            float4 av = *(const float4*)&At[k][ty * 4];
            float4 bv = *(const float4*)&Bs[k][tx * 4];
            float a[4] = {av.x, av.y, av.z, av.w};
            float bb[4] = {bv.x, bv.y, bv.z, bv.w};
#pragma unroll
            for (int i = 0; i < 4; ++i)
#pragma unroll
                for (int j = 0; j < 4; ++j)
                    acc[i][j] = fmaf(a[i], bb[j], acc[i][j]);
        }
        __syncthreads();
    }
#pragma unroll
    for (int i = 0; i < 4; ++i) {
        int row = rb + ty * 4 + i;
        float bv[4] = {0.f, 0.f, 0.f, 0.f};
        if (bias) {
            float sc = ncnt ? ((ncnt[row] > 0) ? 1.0f : 0.0f) : 1.0f;
#pragma unroll
            for (int j = 0; j < 4; ++j) bv[j] = sc * bias[cb + tx * 4 + j];
        }
        float4 o;
        o.x = acc[i][0] + bv[0]; o.y = acc[i][1] + bv[1];
        o.z = acc[i][2] + bv[2]; o.w = acc[i][3] + bv[3];
        *(float4*)(C + (size_t)row * ldc + cb + tx * 4) = o;
    }
}

// ---------------- per-supernode pooled gelu over one 64-col slab ----------------
__device__ __forceinline__ float gelu_tanh(float v) {
    float v3 = v * v * v;
    float t = tanhf(0.7978845608028654f * (v + 0.044715f * v3));
    return 0.5f * v * (1.0f + t);
}

__global__ void pool_slab_kernel(const float* __restrict__ y_slab, const float* __restrict__ z,
                                 const int* __restrict__ nbr, const int* __restrict__ within,
                                 const int* __restrict__ ncnt, float* __restrict__ mh, int slab) {
    int s = blockIdx.x, c = threadIdx.x;   // c in [0,64)
    __shared__ int snbr[KNN];
    __shared__ int swin[KNN];
    if (threadIdx.x < KNN) {
        snbr[threadIdx.x] = nbr[s * KNN + threadIdx.x];
        swin[threadIdx.x] = within[s * KNN + threadIdx.x];
    }
    __syncthreads();
    int cg = slab * 64 + c;
    float zc = z[(size_t)s * 256 + cg];
    float acc = 0.0f;
    for (int j = 0; j < KNN; ++j) {
        if (swin[j]) {
            float v = y_slab[(size_t)snbr[j] * 64 + c] + zc;
            acc += gelu_tanh(v);
        }
    }
    int cnt = ncnt[s];
    mh[(size_t)s * 256 + cg] = acc / (float)max(cnt, 1);
}

extern "C" void kernel_launch(void* const* d_in, const int* in_sizes, int n_in,
                              void* d_out, int out_size, void* d_ws, size_t ws_size,
                              hipStream_t stream) {
    const float* feat  = (const float*)d_in[0];
    const float* pos   = (const float*)d_in[1];
    const int*   sup   = (const int*)d_in[2];
    const float* projW = (const float*)d_in[4];
    const float* projb = (const float*)d_in[5];
    const float* W1    = (const float*)d_in[6];
    const float* b1    = (const float*)d_in[7];
    const float* W2    = (const float*)d_in[8];
    const float* b2    = (const float*)d_in[9];
    float* out = (float*)d_out;

    char* p = (char*)d_ws;
    auto alloc = [&](size_t bytes) { char* q = p; p += (bytes + 255) & ~255ULL; return q; };
    float* x      = (float*)alloc((size_t)N_NODES * HDIM * 4);   // 67.1 MB
    float* y_slab = (float*)alloc((size_t)N_NODES * 64 * 4);     // 16.8 MB (reused per slab)
    float* z      = (float*)alloc((size_t)S_SUP * HDIM * 4);
    float* mh     = (float*)alloc((size_t)S_SUP * HDIM * 4);
    int*   sidx   = (int*)alloc((size_t)N_NODES * 4);
    float* spos   = (float*)alloc((size_t)N_NODES * 4);
    int*   nbr    = (int*)alloc((size_t)S_SUP * KNN * 4);
    int*   within = (int*)alloc((size_t)S_SUP * KNN * 4);
    int*   ncnt   = (int*)alloc((size_t)S_SUP * 4);
    int*   bin_cnt = (int*)alloc((size_t)NBINS * 4);
    int*   cursor  = (int*)alloc((size_t)NBINS * 4);
    int*   bin_ofs = (int*)alloc((size_t)(NBINS + 1) * 4);

    // Workspace guard (~89 MB needed): never write OOB — fail cleanly instead.
    size_t needed = (size_t)(p - (char*)d_ws);
    if (needed > ws_size) {
        hipMemsetAsync(d_out, 0, (size_t)out_size * 4, stream);
        return;
    }

    hipMemsetAsync(bin_cnt, 0, (size_t)NBINS * 4, stream);
    embed_kernel<<<N_NODES / 64, 256, 0, stream>>>(feat, pos, projW, projb, x);
    hist_kernel<<<N_NODES / 256, 256, 0, stream>>>(pos, bin_cnt);
    scan_kernel<<<1, 1024, 0, stream>>>(bin_cnt, bin_ofs, cursor);
    scatter_kernel<<<N_NODES / 256, 256, 0, stream>>>(pos, cursor, sidx, spos);
    topk_kernel<<<S_SUP, 64, 0, stream>>>(pos, sup, bin_ofs, sidx, spos, nbr, within, ncnt);
    // z = x[sup] @ W1b + b1 (dst half of W1)
    gemm64_kernel<<<dim3(S_SUP / 64, 4), 256, 0, stream>>>(x, sup, W1 + 256 * 256, b1, nullptr, z, 256);
    // y in 4 column slabs of 64, pooled immediately (channel-independent)
    for (int slab = 0; slab < 4; ++slab) {
        gemm64_kernel<<<dim3(N_NODES / 64, 1), 256, 0, stream>>>(
            x, nullptr, W1 + slab * 64, nullptr, nullptr, y_slab, 64);
        pool_slab_kernel<<<S_SUP, 64, 0, stream>>>(y_slab, z, nbr, within, ncnt, mh, slab);
    }
    // out = mean_h @ W2 + (cnt>0)*b2
    gemm64_kernel<<<dim3(S_SUP / 64, 4), 256, 0, stream>>>(mh, nullptr, W2, b2, ncnt, out, 256);
}

// Round 11
// 253.598 us; speedup vs baseline: 1.5729x; 1.5729x over previous
//
#include <hip/hip_runtime.h>
#include <hip/hip_bf16.h>
#include <float.h>

#define N_NODES 65536
#define S_SUP   2048
#define HDIM    256
#define KNN     32
#define NBINS   4096
#define CAP     4096

typedef __attribute__((ext_vector_type(8))) __bf16 bf16x8;
typedef __attribute__((ext_vector_type(4))) float  f32x4;

// ---------------- node embedding: xb = bf16(feat@projW + projb + sincos(pos)) ----------------
__global__ __launch_bounds__(256) void embed_kernel(
        const float* __restrict__ feat, const float* __restrict__ pos,
        const float* __restrict__ W, const float* __restrict__ b,
        __hip_bfloat16* __restrict__ xb) {
    __shared__ float sf[64][32];    // feat tile (8 KB)
    __shared__ float sp[64];
    int tid = threadIdx.x;
    int rb = blockIdx.x * 64;
    {
        int r = tid >> 2, kg = tid & 3;
        const float* src = feat + (size_t)(rb + r) * 32 + kg * 8;
        float4 v0 = *(const float4*)(src);
        float4 v1 = *(const float4*)(src + 4);
        *(float4*)&sf[r][kg * 8]     = v0;
        *(float4*)&sf[r][kg * 8 + 4] = v1;
    }
    if (tid < 64) sp[tid] = pos[rb + tid];
    int c = tid;
    float wcol[32];
#pragma unroll
    for (int k = 0; k < 32; ++k) wcol[k] = W[k * 256 + c];   // coalesced, L2-hot
    float bias = b[c];
    const float coef = -logf(10000.0f) / 127.0f;
    float fr = expf((float)(c & 127) * coef);
    bool is_sin = (c < 128);
    __syncthreads();
    for (int r = 0; r < 64; ++r) {
        float acc = bias;
#pragma unroll
        for (int k = 0; k < 32; ++k) acc = fmaf(sf[r][k], wcol[k], acc);
        float e = sp[r] * fr;
        acc += is_sin ? __sinf(e) : __cosf(e);
        xb[(size_t)(rb + r) * 256 + c] = __float2bfloat16(acc);
    }
}

// ---------------- W1 transpose to bf16: w1t[n][k] = W1[k][n], [256][512] ----------------
__global__ void transpose_w1_kernel(const float* __restrict__ W1, __hip_bfloat16* __restrict__ w1t) {
    int k = blockIdx.x;          // 0..511
    int n = threadIdx.x;         // 0..255
    w1t[(size_t)n * 512 + k] = __float2bfloat16(W1[(size_t)k * 256 + n]);
}

// ---------------- binning (counting sort by position) ----------------
__device__ __forceinline__ int pos_bin(float p) {
    int b = (int)(p * (float)NBINS);
    return min(max(b, 0), NBINS - 1);
}

__global__ void hist_kernel(const float* __restrict__ pos, int* __restrict__ bin_cnt) {
    int n = blockIdx.x * blockDim.x + threadIdx.x;
    atomicAdd(&bin_cnt[pos_bin(pos[n])], 1);
}

__global__ void scan_kernel(const int* __restrict__ bin_cnt, int* __restrict__ bin_ofs,
                            int* __restrict__ cursor) {
    __shared__ int sdata[1024];
    int t = threadIdx.x;
    int v[4]; int s = 0;
#pragma unroll
    for (int i = 0; i < 4; ++i) { v[i] = bin_cnt[t * 4 + i]; s += v[i]; }
    sdata[t] = s;
    __syncthreads();
    for (int off = 1; off < 1024; off <<= 1) {
        int add = (t >= off) ? sdata[t - off] : 0;
        __syncthreads();
        sdata[t] += add;
        __syncthreads();
    }
    int run = sdata[t] - s;   // exclusive prefix
#pragma unroll
    for (int i = 0; i < 4; ++i) {
        bin_ofs[t * 4 + i] = run;
        cursor[t * 4 + i]  = run;
        run += v[i];
    }
    if (t == 1023) bin_ofs[NBINS] = run;
}

__global__ void scatter_kernel(const float* __restrict__ pos, int* __restrict__ cursor,
                               int* __restrict__ sidx, float* __restrict__ spos) {
    int n = blockIdx.x * blockDim.x + threadIdx.x;
    float p = pos[n];
    int b = pos_bin(p);
    int dst = atomicAdd(&cursor[b], 1);
    sidx[dst] = n;
    spos[dst] = p;
}

// ---------------- exact top-32 nearest per supernode (1 wave / supernode) ----------------
__global__ void topk_kernel(const float* __restrict__ pos, const int* __restrict__ sup,
                            const int* __restrict__ bin_ofs, const int* __restrict__ sidx,
                            const float* __restrict__ spos,
                            int* __restrict__ nbr, int* __restrict__ within,
                            int* __restrict__ ncnt) {
    __shared__ float cd2[CAP];
    __shared__ int   cidx[CAP];
    __shared__ float rd2[KNN];
    __shared__ int   ridx[KNN];
    int s = blockIdx.x;
    int lane = threadIdx.x;
    float p = pos[sup[s]];
    int hb = pos_bin(p);
    const float BINW = 1.0f / (float)NBINS;
    int ccnt = 0;
    for (int r = 2;; r <<= 1) {
        int lo = max(hb - r, 0), hi = min(hb + r, NBINS - 1);
        int start = bin_ofs[lo], end = bin_ofs[hi + 1];
        ccnt = min(end - start, CAP);
        for (int i = lane; i < ccnt; i += 64) {
            float pp = spos[start + i];
            float d = p - pp;
            cd2[i] = d * d;
            cidx[i] = sidx[start + i];
        }
        __syncthreads();
        float gl = (lo == 0) ? FLT_MAX : (p - (float)lo * BINW);
        float gr = (hi == NBINS - 1) ? FLT_MAX : ((float)(hi + 1) * BINW - p);
        float g = fminf(gl, gr);
        float g2 = (g >= FLT_MAX) ? FLT_MAX : (g * 0.999f) * (g * 0.999f);
        int cw = 0;
        for (int i = lane; i < ccnt; i += 64) cw += (cd2[i] < g2) ? 1 : 0;
        for (int o = 32; o; o >>= 1) cw += __shfl_xor(cw, o);
        if (cw >= KNN || (lo == 0 && hi == NBINS - 1)) break;
        __syncthreads();
    }
    for (int t = 0; t < KNN; ++t) {
        unsigned long long best = ~0ULL;
        int bslot = -1;
        for (int i = lane; i < ccnt; i += 64) {
            unsigned long long k =
                ((unsigned long long)__float_as_uint(cd2[i]) << 32) | (unsigned)cidx[i];
            if (k < best) { best = k; bslot = i; }
        }
        unsigned long long mybest = best;
        for (int o = 32; o; o >>= 1) {
            unsigned long long other = __shfl_xor(best, o);
            best = best < other ? best : other;
        }
        if (mybest == best && bslot >= 0) cd2[bslot] = FLT_MAX;
        if (lane == 0) {
            rd2[t]  = __uint_as_float((unsigned)(best >> 32));
            ridx[t] = (int)(unsigned)(best & 0xffffffffULL);
        }
        __syncthreads();
    }
    const float R2 = (float)(0.005 * 0.005);
    if (lane < KNN) {
        float d2v = rd2[lane];
        int w = (d2v <= R2) ? 1 : 0;
        nbr[s * KNN + lane] = ridx[lane];
        within[s * KNN + lane] = w;
        unsigned long long m = __ballot(w != 0);
        int cnt = __popcll(m & 0xffffffffULL);
        if (lane == 0) ncnt[s] = cnt;
    }
}

// ---------------- gelu (tanh approx, matches jax.nn.gelu default) ----------------
__device__ __forceinline__ float gelu_tanh(float v) {
    float v3 = v * v * v;
    float t = tanhf(0.7978845608028654f * (v + 0.044715f * v3));
    return 0.5f * v * (1.0f + t);
}

// ---- fused per-supernode edge MLP + pool:
//      mh[s] = mean_{j in-radius} gelu( concat(x[nbr_j], x[sup_s]) @ W1 + b1 )
//      MFMA 16x16x32 bf16; M=32 edges (2 tiles), N=256 (4 waves x 4 tiles), K=512.
//      A gathered from global xb; B from L2-resident W1T. No LDS in main loop. ----
__global__ __launch_bounds__(256) void edge_mlp_pool_kernel(
        const __hip_bfloat16* __restrict__ xb_,   // [65536][256]
        const __hip_bfloat16* __restrict__ w1t_,  // [256 n][512 k]
        const float* __restrict__ b1,
        const int* __restrict__ sup,
        const int* __restrict__ nbr, const int* __restrict__ within,
        const int* __restrict__ ncnt, float* __restrict__ mh) {
    const ushort* xb  = (const ushort*)xb_;
    const ushort* w1t = (const ushort*)w1t_;
    int s = blockIdx.x;
    int tid = threadIdx.x;
    int l = tid & 63, w = tid >> 6;
    int lr = l & 15, lg = l >> 4;
    __shared__ int snbr[KNN];
    __shared__ int swin[KNN];
    if (tid < KNN) { snbr[tid] = nbr[s * KNN + tid]; swin[tid] = within[s * KNN + tid]; }
    __syncthreads();
    int ssup = sup[s];
    // A: lane holds row (m0+lr), k = k0 + lg*8 + e   [m89-verified layout family]
    const ushort* arow0 = xb + (size_t)snbr[lr]      * 256;
    const ushort* arow1 = xb + (size_t)snbr[16 + lr] * 256;
    const ushort* asup  = xb + (size_t)ssup          * 256;
    // B: lane holds col (n0+lr), k = k0 + lg*8 + e ; W1T[n][k]
    const ushort* bbase = w1t + (size_t)(w * 64 + lr) * 512;
    int koff = lg * 8;
    f32x4 acc[2][4] = {};
    // low K half: k in [0,256) -> x[nbr]
#pragma unroll 2
    for (int ks = 0; ks < 8; ++ks) {
        int k = ks * 32 + koff;
        bf16x8 a0 = *(const bf16x8*)(arow0 + k);
        bf16x8 a1 = *(const bf16x8*)(arow1 + k);
#pragma unroll
        for (int nt = 0; nt < 4; ++nt) {
            bf16x8 bfr = *(const bf16x8*)(bbase + (size_t)nt * 16 * 512 + k);
            acc[0][nt] = __builtin_amdgcn_mfma_f32_16x16x32_bf16(a0, bfr, acc[0][nt], 0, 0, 0);
            acc[1][nt] = __builtin_amdgcn_mfma_f32_16x16x32_bf16(a1, bfr, acc[1][nt], 0, 0, 0);
        }
    }
    // high K half: virtual k in [256,512) -> x[sup] (same A for both M tiles)
#pragma unroll 2
    for (int ks = 0; ks < 8; ++ks) {
        int k = ks * 32 + koff;
        bf16x8 a = *(const bf16x8*)(asup + k);
#pragma unroll
        for (int nt = 0; nt < 4; ++nt) {
            bf16x8 bfr = *(const bf16x8*)(bbase + (size_t)nt * 16 * 512 + 256 + k);
            acc[0][nt] = __builtin_amdgcn_mfma_f32_16x16x32_bf16(a, bfr, acc[0][nt], 0, 0, 0);
            acc[1][nt] = __builtin_amdgcn_mfma_f32_16x16x32_bf16(a, bfr, acc[1][nt], 0, 0, 0);
        }
    }
    float inv = 1.0f / (float)max(ncnt[s], 1);
    // D: lane holds row (mt*16 + lg*4 + d), col (n0 + nt*16 + lr)
#pragma unroll
    for (int nt = 0; nt < 4; ++nt) {
        int col = w * 64 + nt * 16 + lr;
        float bb = b1[col];
        float msum = 0.f;
#pragma unroll
        for (int mt = 0; mt < 2; ++mt)
#pragma unroll
            for (int d = 0; d < 4; ++d) {
                int row = mt * 16 + lg * 4 + d;
                float v = acc[mt][nt][d] + bb;
                float g = gelu_tanh(v);
                msum += swin[row] ? g : 0.f;
            }
        msum += __shfl_xor(msum, 16);
        msum += __shfl_xor(msum, 32);
        if (lg == 0) mh[(size_t)s * 256 + col] = msum * inv;
    }
}

// ---- f32 GEMM (used for final out = mh@W2 + (cnt>0)*b2): C[M x 256] = A[M x 256]@B[256 x 256] ----
__global__ void gemm64_kernel(const float* __restrict__ A, const int* __restrict__ rowidx,
                              const float* __restrict__ B, const float* __restrict__ bias,
                              const int* __restrict__ ncnt, float* __restrict__ C, int ldc) {
    __shared__ float At[32][68];
    __shared__ float Bs[32][64];
    int tid = threadIdx.x;
    int rb = blockIdx.x * 64, cb = blockIdx.y * 64;
    int tx = tid & 15, ty = tid >> 4;
    float acc[4][4] = {};
    int lr = tid >> 2, kg = tid & 3;
    int arow = rowidx ? rowidx[rb + lr] : (rb + lr);
    const float* aptr = A + (size_t)arow * 256 + kg * 8;
    int k2 = tid >> 3, cg = tid & 7;
    const float* bptr = B + (size_t)k2 * 256 + cb + cg * 8;
    for (int kc = 0; kc < 256; kc += 32) {
        float4 a0 = *(const float4*)(aptr + kc);
        float4 a1 = *(const float4*)(aptr + kc + 4);
        float4 b0 = *(const float4*)(bptr + (size_t)kc * 256);
        float4 b1v = *(const float4*)(bptr + (size_t)kc * 256 + 4);
        At[kg * 8 + 0][lr] = a0.x; At[kg * 8 + 1][lr] = a0.y;
        At[kg * 8 + 2][lr] = a0.z; At[kg * 8 + 3][lr] = a0.w;
        At[kg * 8 + 4][lr] = a1.x; At[kg * 8 + 5][lr] = a1.y;
        At[kg * 8 + 6][lr] = a1.z; At[kg * 8 + 7][lr] = a1.w;
        *(float4*)&Bs[k2][cg * 8]     = b0;
        *(float4*)&Bs[k2][cg * 8 + 4] = b1v;
        __syncthreads();
#pragma unroll
        for (int k = 0; k < 32; ++k) {
            float4 av = *(const float4*)&At[k][ty * 4];
            float4 bv = *(const float4*)&Bs[k][tx * 4];
            float a[4] = {av.x, av.y, av.z, av.w};
            float bb[4] = {bv.x, bv.y, bv.z, bv.w};
#pragma unroll
            for (int i = 0; i < 4; ++i)
#pragma unroll
                for (int j = 0; j < 4; ++j)
                    acc[i][j] = fmaf(a[i], bb[j], acc[i][j]);
        }
        __syncthreads();
    }
#pragma unroll
    for (int i = 0; i < 4; ++i) {
        int row = rb + ty * 4 + i;
        float bv[4] = {0.f, 0.f, 0.f, 0.f};
        if (bias) {
            float sc = ncnt ? ((ncnt[row] > 0) ? 1.0f : 0.0f) : 1.0f;
#pragma unroll
            for (int j = 0; j < 4; ++j) bv[j] = sc * bias[cb + tx * 4 + j];
        }
        float4 o;
        o.x = acc[i][0] + bv[0]; o.y = acc[i][1] + bv[1];
        o.z = acc[i][2] + bv[2]; o.w = acc[i][3] + bv[3];
        *(float4*)(C + (size_t)row * ldc + cb + tx * 4) = o;
    }
}

extern "C" void kernel_launch(void* const* d_in, const int* in_sizes, int n_in,
                              void* d_out, int out_size, void* d_ws, size_t ws_size,
                              hipStream_t stream) {
    const float* feat  = (const float*)d_in[0];
    const float* pos   = (const float*)d_in[1];
    const int*   sup   = (const int*)d_in[2];
    const float* projW = (const float*)d_in[4];
    const float* projb = (const float*)d_in[5];
    const float* W1    = (const float*)d_in[6];
    const float* b1    = (const float*)d_in[7];
    const float* W2    = (const float*)d_in[8];
    const float* b2    = (const float*)d_in[9];
    float* out = (float*)d_out;

    char* p = (char*)d_ws;
    auto alloc = [&](size_t bytes) { char* q = p; p += (bytes + 255) & ~255ULL; return q; };
    __hip_bfloat16* xb  = (__hip_bfloat16*)alloc((size_t)N_NODES * HDIM * 2);  // 33.6 MB
    __hip_bfloat16* w1t = (__hip_bfloat16*)alloc((size_t)256 * 512 * 2);       // 256 KB
    float* mh     = (float*)alloc((size_t)S_SUP * HDIM * 4);
    int*   sidx   = (int*)alloc((size_t)N_NODES * 4);
    float* spos   = (float*)alloc((size_t)N_NODES * 4);
    int*   nbr    = (int*)alloc((size_t)S_SUP * KNN * 4);
    int*   within = (int*)alloc((size_t)S_SUP * KNN * 4);
    int*   ncnt   = (int*)alloc((size_t)S_SUP * 4);
    int*   bin_cnt = (int*)alloc((size_t)NBINS * 4);
    int*   cursor  = (int*)alloc((size_t)NBINS * 4);
    int*   bin_ofs = (int*)alloc((size_t)(NBINS + 1) * 4);

    // Workspace guard (~38 MB needed): never write OOB — fail cleanly instead.
    size_t needed = (size_t)(p - (char*)d_ws);
    if (needed > ws_size) {
        hipMemsetAsync(d_out, 0, (size_t)out_size * 4, stream);
        return;
    }

    hipMemsetAsync(bin_cnt, 0, (size_t)NBINS * 4, stream);
    embed_kernel<<<N_NODES / 64, 256, 0, stream>>>(feat, pos, projW, projb, xb);
    transpose_w1_kernel<<<512, 256, 0, stream>>>(W1, w1t);
    hist_kernel<<<N_NODES / 256, 256, 0, stream>>>(pos, bin_cnt);
    scan_kernel<<<1, 1024, 0, stream>>>(bin_cnt, bin_ofs, cursor);
    scatter_kernel<<<N_NODES / 256, 256, 0, stream>>>(pos, cursor, sidx, spos);
    topk_kernel<<<S_SUP, 64, 0, stream>>>(pos, sup, bin_ofs, sidx, spos, nbr, within, ncnt);
    edge_mlp_pool_kernel<<<S_SUP, 256, 0, stream>>>(xb, w1t, b1, sup, nbr, within, ncnt, mh);
    gemm64_kernel<<<dim3(S_SUP / 64, 4), 256, 0, stream>>>(mh, nullptr, W2, b2, ncnt, out, 256);
}

// Round 12
// 246.040 us; speedup vs baseline: 1.6213x; 1.0307x over previous
//
#include <hip/hip_runtime.h>
#include <hip/hip_bf16.h>
#include <float.h>

#define N_NODES 65536
#define S_SUP   2048
#define HDIM    256
#define KNN     32
#define NBINS   4096
#define CAP     4096
#define GSUP    4

typedef __attribute__((ext_vector_type(8))) __bf16 bf16x8;
typedef __attribute__((ext_vector_type(4))) float  f32x4;

// ---------------- node embedding: xb = bf16(feat@projW + projb + sincos(pos)) ----------------
__global__ __launch_bounds__(256) void embed_kernel(
        const float* __restrict__ feat, const float* __restrict__ pos,
        const float* __restrict__ W, const float* __restrict__ b,
        __hip_bfloat16* __restrict__ xb) {
    __shared__ float sf[64][32];    // feat tile (8 KB)
    __shared__ float sp[64];
    int tid = threadIdx.x;
    int rb = blockIdx.x * 64;
    {
        int r = tid >> 2, kg = tid & 3;
        const float* src = feat + (size_t)(rb + r) * 32 + kg * 8;
        float4 v0 = *(const float4*)(src);
        float4 v1 = *(const float4*)(src + 4);
        *(float4*)&sf[r][kg * 8]     = v0;
        *(float4*)&sf[r][kg * 8 + 4] = v1;
    }
    if (tid < 64) sp[tid] = pos[rb + tid];
    int c = tid;
    float wcol[32];
#pragma unroll
    for (int k = 0; k < 32; ++k) wcol[k] = W[k * 256 + c];   // coalesced, L2-hot
    float bias = b[c];
    const float coef = -logf(10000.0f) / 127.0f;
    float fr = expf((float)(c & 127) * coef);
    bool is_sin = (c < 128);
    __syncthreads();
    for (int r = 0; r < 64; ++r) {
        float acc = bias;
#pragma unroll
        for (int k = 0; k < 32; ++k) acc = fmaf(sf[r][k], wcol[k], acc);
        float e = sp[r] * fr;
        acc += is_sin ? __sinf(e) : __cosf(e);
        xb[(size_t)(rb + r) * 256 + c] = __float2bfloat16(acc);
    }
}

// ---------------- W1 transpose to bf16: w1t[n][k] = W1[k][n], [256][512] ----------------
__global__ void transpose_w1_kernel(const float* __restrict__ W1, __hip_bfloat16* __restrict__ w1t) {
    int k = blockIdx.x;          // 0..511
    int n = threadIdx.x;         // 0..255
    w1t[(size_t)n * 512 + k] = __float2bfloat16(W1[(size_t)k * 256 + n]);
}

// ---------------- binning (counting sort by position) ----------------
__device__ __forceinline__ int pos_bin(float p) {
    int b = (int)(p * (float)NBINS);
    return min(max(b, 0), NBINS - 1);
}

__global__ void hist_kernel(const float* __restrict__ pos, int* __restrict__ bin_cnt) {
    int n = blockIdx.x * blockDim.x + threadIdx.x;
    atomicAdd(&bin_cnt[pos_bin(pos[n])], 1);
}

__global__ void scan_kernel(const int* __restrict__ bin_cnt, int* __restrict__ bin_ofs,
                            int* __restrict__ cursor) {
    __shared__ int sdata[1024];
    int t = threadIdx.x;
    int v[4]; int s = 0;
#pragma unroll
    for (int i = 0; i < 4; ++i) { v[i] = bin_cnt[t * 4 + i]; s += v[i]; }
    sdata[t] = s;
    __syncthreads();
    for (int off = 1; off < 1024; off <<= 1) {
        int add = (t >= off) ? sdata[t - off] : 0;
        __syncthreads();
        sdata[t] += add;
        __syncthreads();
    }
    int run = sdata[t] - s;   // exclusive prefix
#pragma unroll
    for (int i = 0; i < 4; ++i) {
        bin_ofs[t * 4 + i] = run;
        cursor[t * 4 + i]  = run;
        run += v[i];
    }
    if (t == 1023) bin_ofs[NBINS] = run;
}

__global__ void scatter_kernel(const float* __restrict__ pos, int* __restrict__ cursor,
                               int* __restrict__ sidx, float* __restrict__ spos) {
    int n = blockIdx.x * blockDim.x + threadIdx.x;
    float p = pos[n];
    int b = pos_bin(p);
    int dst = atomicAdd(&cursor[b], 1);
    sidx[dst] = n;
    spos[dst] = p;
}

// ---------------- exact top-32 nearest per supernode (1 wave / supernode) ----------------
__global__ void topk_kernel(const float* __restrict__ pos, const int* __restrict__ sup,
                            const int* __restrict__ bin_ofs, const int* __restrict__ sidx,
                            const float* __restrict__ spos,
                            int* __restrict__ nbr, int* __restrict__ within,
                            int* __restrict__ ncnt) {
    __shared__ float cd2[CAP];
    __shared__ int   cidx[CAP];
    __shared__ float rd2[KNN];
    __shared__ int   ridx[KNN];
    int s = blockIdx.x;
    int lane = threadIdx.x;
    float p = pos[sup[s]];
    int hb = pos_bin(p);
    const float BINW = 1.0f / (float)NBINS;
    int ccnt = 0;
    for (int r = 2;; r <<= 1) {
        int lo = max(hb - r, 0), hi = min(hb + r, NBINS - 1);
        int start = bin_ofs[lo], end = bin_ofs[hi + 1];
        ccnt = min(end - start, CAP);
        for (int i = lane; i < ccnt; i += 64) {
            float pp = spos[start + i];
            float d = p - pp;
            cd2[i] = d * d;
            cidx[i] = sidx[start + i];
        }
        __syncthreads();
        float gl = (lo == 0) ? FLT_MAX : (p - (float)lo * BINW);
        float gr = (hi == NBINS - 1) ? FLT_MAX : ((float)(hi + 1) * BINW - p);
        float g = fminf(gl, gr);
        float g2 = (g >= FLT_MAX) ? FLT_MAX : (g * 0.999f) * (g * 0.999f);
        int cw = 0;
        for (int i = lane; i < ccnt; i += 64) cw += (cd2[i] < g2) ? 1 : 0;
        for (int o = 32; o; o >>= 1) cw += __shfl_xor(cw, o);
        if (cw >= KNN || (lo == 0 && hi == NBINS - 1)) break;
        __syncthreads();
    }
    for (int t = 0; t < KNN; ++t) {
        unsigned long long best = ~0ULL;
        int bslot = -1;
        for (int i = lane; i < ccnt; i += 64) {
            unsigned long long k =
                ((unsigned long long)__float_as_uint(cd2[i]) << 32) | (unsigned)cidx[i];
            if (k < best) { best = k; bslot = i; }
        }
        unsigned long long mybest = best;
        for (int o = 32; o; o >>= 1) {
            unsigned long long other = __shfl_xor(best, o);
            best = best < other ? best : other;
        }
        if (mybest == best && bslot >= 0) cd2[bslot] = FLT_MAX;
        if (lane == 0) {
            rd2[t]  = __uint_as_float((unsigned)(best >> 32));
            ridx[t] = (int)(unsigned)(best & 0xffffffffULL);
        }
        __syncthreads();
    }
    const float R2 = (float)(0.005 * 0.005);
    if (lane < KNN) {
        float d2v = rd2[lane];
        int w = (d2v <= R2) ? 1 : 0;
        nbr[s * KNN + lane] = ridx[lane];
        within[s * KNN + lane] = w;
        unsigned long long m = __ballot(w != 0);
        int cnt = __popcll(m & 0xffffffffULL);
        if (lane == 0) ncnt[s] = cnt;
    }
}

// ---------------- gelu (tanh approx, matches jax.nn.gelu default) ----------------
__device__ __forceinline__ float gelu_tanh(float v) {
    float v3 = v * v * v;
    float t = tanhf(0.7978845608028654f * (v + 0.044715f * v3));
    return 0.5f * v * (1.0f + t);
}

// ---- fused per-supernode edge MLP + pool, G=4 supernodes per block:
//      mh[s] = mean_{j in-radius} gelu( concat(x[nbr_j], x[sup_s]) @ W1 + b1 )
//      Per k-step each wave loads its 4 B-frags ONCE and reuses across 4 supernodes
//      (32 MFMA per B-load set) -> 4x less L2 B-traffic + 4x ILP for latency hiding. ----
__global__ __launch_bounds__(256) void edge_mlp_pool_kernel(
        const __hip_bfloat16* __restrict__ xb_,   // [65536][256]
        const __hip_bfloat16* __restrict__ w1t_,  // [256 n][512 k]
        const float* __restrict__ b1,
        const int* __restrict__ sup,
        const int* __restrict__ nbr, const int* __restrict__ within,
        const int* __restrict__ ncnt, float* __restrict__ mh) {
    const ushort* xb  = (const ushort*)xb_;
    const ushort* w1t = (const ushort*)w1t_;
    int s0 = blockIdx.x * GSUP;
    int tid = threadIdx.x;
    int l = tid & 63, w = tid >> 6;
    int lr = l & 15, lg = l >> 4;
    __shared__ int snbr[GSUP][KNN];
    __shared__ int swin[GSUP][KNN];
    __shared__ int ssup[GSUP];
    if (tid < GSUP * KNN) {
        int g = tid >> 5, j = tid & 31;
        snbr[g][j] = nbr[(s0 + g) * KNN + j];
        swin[g][j] = within[(s0 + g) * KNN + j];
    }
    if (tid < GSUP) ssup[tid] = sup[s0 + tid];
    __syncthreads();
    // A row pointers per supernode (m89-verified layout: A row=lane&15, k=(lane>>4)*8+e)
    const ushort* ar0[GSUP];
    const ushort* ar1[GSUP];
    const ushort* asp[GSUP];
#pragma unroll
    for (int g = 0; g < GSUP; ++g) {
        ar0[g] = xb + (size_t)snbr[g][lr]      * 256;
        ar1[g] = xb + (size_t)snbr[g][16 + lr] * 256;
        asp[g] = xb + (size_t)ssup[g]          * 256;
    }
    const ushort* bbase = w1t + (size_t)(w * 64 + lr) * 512;
    int koff = lg * 8;
    f32x4 acc[GSUP][2][4] = {};
    // low K half: k in [0,256) -> x[nbr]
#pragma unroll 1
    for (int ks = 0; ks < 8; ++ks) {
        int k = ks * 32 + koff;
        bf16x8 bfr[4];
#pragma unroll
        for (int nt = 0; nt < 4; ++nt) bfr[nt] = *(const bf16x8*)(bbase + (size_t)nt * 16 * 512 + k);
#pragma unroll
        for (int g = 0; g < GSUP; ++g) {
            bf16x8 a0 = *(const bf16x8*)(ar0[g] + k);
            bf16x8 a1 = *(const bf16x8*)(ar1[g] + k);
#pragma unroll
            for (int nt = 0; nt < 4; ++nt) {
                acc[g][0][nt] = __builtin_amdgcn_mfma_f32_16x16x32_bf16(a0, bfr[nt], acc[g][0][nt], 0, 0, 0);
                acc[g][1][nt] = __builtin_amdgcn_mfma_f32_16x16x32_bf16(a1, bfr[nt], acc[g][1][nt], 0, 0, 0);
            }
        }
    }
    // high K half: virtual k in [256,512) -> x[sup] (same A for both M tiles)
#pragma unroll 1
    for (int ks = 0; ks < 8; ++ks) {
        int k = ks * 32 + koff;
        bf16x8 bfr[4];
#pragma unroll
        for (int nt = 0; nt < 4; ++nt) bfr[nt] = *(const bf16x8*)(bbase + (size_t)nt * 16 * 512 + 256 + k);
#pragma unroll
        for (int g = 0; g < GSUP; ++g) {
            bf16x8 a = *(const bf16x8*)(asp[g] + k);
#pragma unroll
            for (int nt = 0; nt < 4; ++nt) {
                acc[g][0][nt] = __builtin_amdgcn_mfma_f32_16x16x32_bf16(a, bfr[nt], acc[g][0][nt], 0, 0, 0);
                acc[g][1][nt] = __builtin_amdgcn_mfma_f32_16x16x32_bf16(a, bfr[nt], acc[g][1][nt], 0, 0, 0);
            }
        }
    }
    // epilogue: D lane holds row (mt*16 + lg*4 + d), col (w*64 + nt*16 + lr)
#pragma unroll
    for (int nt = 0; nt < 4; ++nt) {
        int col = w * 64 + nt * 16 + lr;
        float bb = b1[col];
#pragma unroll
        for (int g = 0; g < GSUP; ++g) {
            float msum = 0.f;
#pragma unroll
            for (int mt = 0; mt < 2; ++mt)
#pragma unroll
                for (int d = 0; d < 4; ++d) {
                    int row = mt * 16 + lg * 4 + d;
                    float v = acc[g][mt][nt][d] + bb;
                    float gl = gelu_tanh(v);
                    msum += swin[g][row] ? gl : 0.f;
                }
            msum += __shfl_xor(msum, 16);
            msum += __shfl_xor(msum, 32);
            if (lg == 0) {
                float inv = 1.0f / (float)max(ncnt[s0 + g], 1);
                mh[(size_t)(s0 + g) * 256 + col] = msum * inv;
            }
        }
    }
}

// ---- f32 GEMM (used for final out = mh@W2 + (cnt>0)*b2): C[M x 256] = A[M x 256]@B[256 x 256] ----
__global__ void gemm64_kernel(const float* __restrict__ A, const int* __restrict__ rowidx,
                              const float* __restrict__ B, const float* __restrict__ bias,
                              const int* __restrict__ ncnt, float* __restrict__ C, int ldc) {
    __shared__ float At[32][68];
    __shared__ float Bs[32][64];
    int tid = threadIdx.x;
    int rb = blockIdx.x * 64, cb = blockIdx.y * 64;
    int tx = tid & 15, ty = tid >> 4;
    float acc[4][4] = {};
    int lr = tid >> 2, kg = tid & 3;
    int arow = rowidx ? rowidx[rb + lr] : (rb + lr);
    const float* aptr = A + (size_t)arow * 256 + kg * 8;
    int k2 = tid >> 3, cg = tid & 7;
    const float* bptr = B + (size_t)k2 * 256 + cb + cg * 8;
    for (int kc = 0; kc < 256; kc += 32) {
        float4 a0 = *(const float4*)(aptr + kc);
        float4 a1 = *(const float4*)(aptr + kc + 4);
        float4 b0 = *(const float4*)(bptr + (size_t)kc * 256);
        float4 b1v = *(const float4*)(bptr + (size_t)kc * 256 + 4);
        At[kg * 8 + 0][lr] = a0.x; At[kg * 8 + 1][lr] = a0.y;
        At[kg * 8 + 2][lr] = a0.z; At[kg * 8 + 3][lr] = a0.w;
        At[kg * 8 + 4][lr] = a1.x; At[kg * 8 + 5][lr] = a1.y;
        At[kg * 8 + 6][lr] = a1.z; At[kg * 8 + 7][lr] = a1.w;
        *(float4*)&Bs[k2][cg * 8]     = b0;
        *(float4*)&Bs[k2][cg * 8 + 4] = b1v;
        __syncthreads();
#pragma unroll
        for (int k = 0; k < 32; ++k) {
            float4 av = *(const float4*)&At[k][ty * 4];
            float4 bv = *(const float4*)&Bs[k][tx * 4];
            float a[4] = {av.x, av.y, av.z, av.w};
            float bb[4] = {bv.x, bv.y, bv.z, bv.w};
#pragma unroll
            for (int i = 0; i < 4; ++i)
#pragma unroll
                for (int j = 0; j < 4; ++j)
                    acc[i][j] = fmaf(a[i], bb[j], acc[i][j]);
        }
        __syncthreads();
    }
#pragma unroll
    for (int i = 0; i < 4; ++i) {
        int row = rb + ty * 4 + i;
        float bv[4] = {0.f, 0.f, 0.f, 0.f};
        if (bias) {
            float sc = ncnt ? ((ncnt[row] > 0) ? 1.0f : 0.0f) : 1.0f;
#pragma unroll
            for (int j = 0; j < 4; ++j) bv[j] = sc * bias[cb + tx * 4 + j];
        }
        float4 o;
        o.x = acc[i][0] + bv[0]; o.y = acc[i][1] + bv[1];
        o.z = acc[i][2] + bv[2]; o.w = acc[i][3] + bv[3];
        *(float4*)(C + (size_t)row * ldc + cb + tx * 4) = o;
    }
}

extern "C" void kernel_launch(void* const* d_in, const int* in_sizes, int n_in,
                              void* d_out, int out_size, void* d_ws, size_t ws_size,
                              hipStream_t stream) {
    const float* feat  = (const float*)d_in[0];
    const float* pos   = (const float*)d_in[1];
    const int*   sup   = (const int*)d_in[2];
    const float* projW = (const float*)d_in[4];
    const float* projb = (const float*)d_in[5];
    const float* W1    = (const float*)d_in[6];
    const float* b1    = (const float*)d_in[7];
    const float* W2    = (const float*)d_in[8];
    const float* b2    = (const float*)d_in[9];
    float* out = (float*)d_out;

    char* p = (char*)d_ws;
    auto alloc = [&](size_t bytes) { char* q = p; p += (bytes + 255) & ~255ULL; return q; };
    __hip_bfloat16* xb  = (__hip_bfloat16*)alloc((size_t)N_NODES * HDIM * 2);  // 33.6 MB
    __hip_bfloat16* w1t = (__hip_bfloat16*)alloc((size_t)256 * 512 * 2);       // 256 KB
    float* mh     = (float*)alloc((size_t)S_SUP * HDIM * 4);
    int*   sidx   = (int*)alloc((size_t)N_NODES * 4);
    float* spos   = (float*)alloc((size_t)N_NODES * 4);
    int*   nbr    = (int*)alloc((size_t)S_SUP * KNN * 4);
    int*   within = (int*)alloc((size_t)S_SUP * KNN * 4);
    int*   ncnt   = (int*)alloc((size_t)S_SUP * 4);
    int*   bin_cnt = (int*)alloc((size_t)NBINS * 4);
    int*   cursor  = (int*)alloc((size_t)NBINS * 4);
    int*   bin_ofs = (int*)alloc((size_t)(NBINS + 1) * 4);

    // Workspace guard (~38 MB needed): never write OOB — fail cleanly instead.
    size_t needed = (size_t)(p - (char*)d_ws);
    if (needed > ws_size) {
        hipMemsetAsync(d_out, 0, (size_t)out_size * 4, stream);
        return;
    }

    hipMemsetAsync(bin_cnt, 0, (size_t)NBINS * 4, stream);
    embed_kernel<<<N_NODES / 64, 256, 0, stream>>>(feat, pos, projW, projb, xb);
    transpose_w1_kernel<<<512, 256, 0, stream>>>(W1, w1t);
    hist_kernel<<<N_NODES / 256, 256, 0, stream>>>(pos, bin_cnt);
    scan_kernel<<<1, 1024, 0, stream>>>(bin_cnt, bin_ofs, cursor);
    scatter_kernel<<<N_NODES / 256, 256, 0, stream>>>(pos, cursor, sidx, spos);
    topk_kernel<<<S_SUP, 64, 0, stream>>>(pos, sup, bin_ofs, sidx, spos, nbr, within, ncnt);
    edge_mlp_pool_kernel<<<S_SUP / GSUP, 256, 0, stream>>>(xb, w1t, b1, sup, nbr, within, ncnt, mh);
    gemm64_kernel<<<dim3(S_SUP / 64, 4), 256, 0, stream>>>(mh, nullptr, W2, b2, ncnt, out, 256);
}

// Round 13
// 218.835 us; speedup vs baseline: 1.8228x; 1.1243x over previous
//
#include <hip/hip_runtime.h>
#include <hip/hip_bf16.h>
#include <float.h>

#define N_NODES 65536
#define S_SUP   2048
#define HDIM    256
#define KNN     32
#define NBINS   4096
#define CAP     4096
#define GSUP    2

typedef __attribute__((ext_vector_type(8))) __bf16 bf16x8;
typedef __attribute__((ext_vector_type(4))) float  f32x4;

// ---------------- node embedding: xb = bf16(feat@projW + projb + sincos(pos)) ----------------
__global__ __launch_bounds__(256) void embed_kernel(
        const float* __restrict__ feat, const float* __restrict__ pos,
        const float* __restrict__ W, const float* __restrict__ b,
        __hip_bfloat16* __restrict__ xb) {
    __shared__ float sf[64][32];    // feat tile (8 KB)
    __shared__ float sp[64];
    int tid = threadIdx.x;
    int rb = blockIdx.x * 64;
    {
        int r = tid >> 2, kg = tid & 3;
        const float* src = feat + (size_t)(rb + r) * 32 + kg * 8;
        float4 v0 = *(const float4*)(src);
        float4 v1 = *(const float4*)(src + 4);
        *(float4*)&sf[r][kg * 8]     = v0;
        *(float4*)&sf[r][kg * 8 + 4] = v1;
    }
    if (tid < 64) sp[tid] = pos[rb + tid];
    int c = tid;
    float wcol[32];
#pragma unroll
    for (int k = 0; k < 32; ++k) wcol[k] = W[k * 256 + c];   // coalesced, L2-hot
    float bias = b[c];
    const float coef = -logf(10000.0f) / 127.0f;
    float fr = expf((float)(c & 127) * coef);
    bool is_sin = (c < 128);
    __syncthreads();
    for (int r = 0; r < 64; ++r) {
        float acc = bias;
#pragma unroll
        for (int k = 0; k < 32; ++k) acc = fmaf(sf[r][k], wcol[k], acc);
        float e = sp[r] * fr;
        acc += is_sin ? __sinf(e) : __cosf(e);
        xb[(size_t)(rb + r) * 256 + c] = __float2bfloat16(acc);
    }
}

// ---- W1 -> MFMA-fragment-ordered bf16 layout:
//      w1f[((ks*16 + ntg)*64 + lane)*8 + e] = W1[k][n],
//      n = ntg*16 + (lane&15), k = ks*32 + (lane>>4)*8 + e   (ks 0..15 covers K=512)
//      A wave's B-fragment load becomes base + lane*16B: fully coalesced. ----
__global__ void transpose_w1_kernel(const float* __restrict__ W1, __hip_bfloat16* __restrict__ w1f) {
    int tile = blockIdx.x;            // 0..255 : ks = tile>>4, ntg = tile&15
    int ks = tile >> 4, ntg = tile & 15;
    int tid = threadIdx.x;
    for (int i = tid; i < 512; i += 256) {
        int l = i >> 3, e = i & 7;
        int n = ntg * 16 + (l & 15);
        int k = ks * 32 + ((l >> 4) << 3) + e;
        w1f[(size_t)tile * 512 + i] = __float2bfloat16(W1[(size_t)k * 256 + n]);
    }
}

// ---------------- binning (counting sort by position) ----------------
__device__ __forceinline__ int pos_bin(float p) {
    int b = (int)(p * (float)NBINS);
    return min(max(b, 0), NBINS - 1);
}

__global__ void hist_kernel(const float* __restrict__ pos, int* __restrict__ bin_cnt) {
    int n = blockIdx.x * blockDim.x + threadIdx.x;
    atomicAdd(&bin_cnt[pos_bin(pos[n])], 1);
}

__global__ void scan_kernel(const int* __restrict__ bin_cnt, int* __restrict__ bin_ofs,
                            int* __restrict__ cursor) {
    __shared__ int sdata[1024];
    int t = threadIdx.x;
    int v[4]; int s = 0;
#pragma unroll
    for (int i = 0; i < 4; ++i) { v[i] = bin_cnt[t * 4 + i]; s += v[i]; }
    sdata[t] = s;
    __syncthreads();
    for (int off = 1; off < 1024; off <<= 1) {
        int add = (t >= off) ? sdata[t - off] : 0;
        __syncthreads();
        sdata[t] += add;
        __syncthreads();
    }
    int run = sdata[t] - s;   // exclusive prefix
#pragma unroll
    for (int i = 0; i < 4; ++i) {
        bin_ofs[t * 4 + i] = run;
        cursor[t * 4 + i]  = run;
        run += v[i];
    }
    if (t == 1023) bin_ofs[NBINS] = run;
}

__global__ void scatter_kernel(const float* __restrict__ pos, int* __restrict__ cursor,
                               int* __restrict__ sidx, float* __restrict__ spos) {
    int n = blockIdx.x * blockDim.x + threadIdx.x;
    float p = pos[n];
    int b = pos_bin(p);
    int dst = atomicAdd(&cursor[b], 1);
    sidx[dst] = n;
    spos[dst] = p;
}

// ---------------- exact top-32 nearest per supernode (1 wave / supernode) ----------------
__global__ void topk_kernel(const float* __restrict__ pos, const int* __restrict__ sup,
                            const int* __restrict__ bin_ofs, const int* __restrict__ sidx,
                            const float* __restrict__ spos,
                            int* __restrict__ nbr, int* __restrict__ within,
                            int* __restrict__ ncnt) {
    __shared__ float cd2[CAP];
    __shared__ int   cidx[CAP];
    __shared__ float rd2[KNN];
    __shared__ int   ridx[KNN];
    int s = blockIdx.x;
    int lane = threadIdx.x;
    float p = pos[sup[s]];
    int hb = pos_bin(p);
    const float BINW = 1.0f / (float)NBINS;
    int ccnt = 0;
    for (int r = 2;; r <<= 1) {
        int lo = max(hb - r, 0), hi = min(hb + r, NBINS - 1);
        int start = bin_ofs[lo], end = bin_ofs[hi + 1];
        ccnt = min(end - start, CAP);
        for (int i = lane; i < ccnt; i += 64) {
            float pp = spos[start + i];
            float d = p - pp;
            cd2[i] = d * d;
            cidx[i] = sidx[start + i];
        }
        __syncthreads();
        float gl = (lo == 0) ? FLT_MAX : (p - (float)lo * BINW);
        float gr = (hi == NBINS - 1) ? FLT_MAX : ((float)(hi + 1) * BINW - p);
        float g = fminf(gl, gr);
        float g2 = (g >= FLT_MAX) ? FLT_MAX : (g * 0.999f) * (g * 0.999f);
        int cw = 0;
        for (int i = lane; i < ccnt; i += 64) cw += (cd2[i] < g2) ? 1 : 0;
        for (int o = 32; o; o >>= 1) cw += __shfl_xor(cw, o);
        if (cw >= KNN || (lo == 0 && hi == NBINS - 1)) break;
        __syncthreads();
    }
    for (int t = 0; t < KNN; ++t) {
        unsigned long long best = ~0ULL;
        int bslot = -1;
        for (int i = lane; i < ccnt; i += 64) {
            unsigned long long k =
                ((unsigned long long)__float_as_uint(cd2[i]) << 32) | (unsigned)cidx[i];
            if (k < best) { best = k; bslot = i; }
        }
        unsigned long long mybest = best;
        for (int o = 32; o; o >>= 1) {
            unsigned long long other = __shfl_xor(best, o);
            best = best < other ? best : other;
        }
        if (mybest == best && bslot >= 0) cd2[bslot] = FLT_MAX;
        if (lane == 0) {
            rd2[t]  = __uint_as_float((unsigned)(best >> 32));
            ridx[t] = (int)(unsigned)(best & 0xffffffffULL);
        }
        __syncthreads();
    }
    const float R2 = (float)(0.005 * 0.005);
    if (lane < KNN) {
        float d2v = rd2[lane];
        int w = (d2v <= R2) ? 1 : 0;
        nbr[s * KNN + lane] = ridx[lane];
        within[s * KNN + lane] = w;
        unsigned long long m = __ballot(w != 0);
        int cnt = __popcll(m & 0xffffffffULL);
        if (lane == 0) ncnt[s] = cnt;
    }
}

// ---------------- gelu (tanh approx, matches jax.nn.gelu default) ----------------
__device__ __forceinline__ float gelu_tanh(float v) {
    float v3 = v * v * v;
    float t = tanhf(0.7978845608028654f * (v + 0.044715f * v3));
    return 0.5f * v * (1.0f + t);
}

// ---- fused per-supernode edge MLP + pool, G=2 supernodes per block, frag-ordered B:
//      mh[s] = mean_{j in-radius} gelu( concat(x[nbr_j], x[sup_s]) @ W1 + b1 ) ----
__global__ __launch_bounds__(256) void edge_mlp_pool_kernel(
        const __hip_bfloat16* __restrict__ xb_,   // [65536][256]
        const __hip_bfloat16* __restrict__ w1f_,  // frag-ordered [16 ks][16 ntg][64 lane][8 e]
        const float* __restrict__ b1,
        const int* __restrict__ sup,
        const int* __restrict__ nbr, const int* __restrict__ within,
        const int* __restrict__ ncnt, float* __restrict__ mh) {
    const ushort* xb  = (const ushort*)xb_;
    const ushort* w1f = (const ushort*)w1f_;
    int s0 = blockIdx.x * GSUP;
    int tid = threadIdx.x;
    int l = tid & 63, w = tid >> 6;
    int lr = l & 15, lg = l >> 4;
    __shared__ int snbr[GSUP][KNN];
    __shared__ int swin[GSUP][KNN];
    __shared__ int ssup[GSUP];
    if (tid < GSUP * KNN) {
        int g = tid >> 5, j = tid & 31;
        snbr[g][j] = nbr[(s0 + g) * KNN + j];
        swin[g][j] = within[(s0 + g) * KNN + j];
    }
    if (tid < GSUP) ssup[tid] = sup[s0 + tid];
    __syncthreads();
    // A row pointers (m89-verified layout: A row=lane&15, k=(lane>>4)*8+e)
    const ushort* ar0[GSUP];
    const ushort* ar1[GSUP];
    const ushort* asp[GSUP];
#pragma unroll
    for (int g = 0; g < GSUP; ++g) {
        ar0[g] = xb + (size_t)snbr[g][lr]      * 256;
        ar1[g] = xb + (size_t)snbr[g][16 + lr] * 256;
        asp[g] = xb + (size_t)ssup[g]          * 256;
    }
    int koff = lg * 8;
    f32x4 acc[GSUP][2][4] = {};
    // low K half (ks 0..7): k in [0,256) -> x[nbr]
#pragma unroll 1
    for (int ks = 0; ks < 8; ++ks) {
        int k = ks * 32 + koff;
        bf16x8 bfr[4];
#pragma unroll
        for (int nt = 0; nt < 4; ++nt)
            bfr[nt] = *(const bf16x8*)(w1f + ((size_t)(ks * 16 + w * 4 + nt) * 64 + l) * 8);
#pragma unroll
        for (int g = 0; g < GSUP; ++g) {
            bf16x8 a0 = *(const bf16x8*)(ar0[g] + k);
            bf16x8 a1 = *(const bf16x8*)(ar1[g] + k);
#pragma unroll
            for (int nt = 0; nt < 4; ++nt) {
                acc[g][0][nt] = __builtin_amdgcn_mfma_f32_16x16x32_bf16(a0, bfr[nt], acc[g][0][nt], 0, 0, 0);
                acc[g][1][nt] = __builtin_amdgcn_mfma_f32_16x16x32_bf16(a1, bfr[nt], acc[g][1][nt], 0, 0, 0);
            }
        }
    }
    // high K half (ks 8..15): virtual k in [256,512) -> x[sup] (same A for both M tiles)
#pragma unroll 1
    for (int ks = 8; ks < 16; ++ks) {
        int k = (ks - 8) * 32 + koff;
        bf16x8 bfr[4];
#pragma unroll
        for (int nt = 0; nt < 4; ++nt)
            bfr[nt] = *(const bf16x8*)(w1f + ((size_t)(ks * 16 + w * 4 + nt) * 64 + l) * 8);
#pragma unroll
        for (int g = 0; g < GSUP; ++g) {
            bf16x8 a = *(const bf16x8*)(asp[g] + k);
#pragma unroll
            for (int nt = 0; nt < 4; ++nt) {
                acc[g][0][nt] = __builtin_amdgcn_mfma_f32_16x16x32_bf16(a, bfr[nt], acc[g][0][nt], 0, 0, 0);
                acc[g][1][nt] = __builtin_amdgcn_mfma_f32_16x16x32_bf16(a, bfr[nt], acc[g][1][nt], 0, 0, 0);
            }
        }
    }
    // epilogue: D lane holds row (mt*16 + lg*4 + d), col (w*64 + nt*16 + lr)
#pragma unroll
    for (int nt = 0; nt < 4; ++nt) {
        int col = w * 64 + nt * 16 + lr;
        float bb = b1[col];
#pragma unroll
        for (int g = 0; g < GSUP; ++g) {
            float msum = 0.f;
#pragma unroll
            for (int mt = 0; mt < 2; ++mt)
#pragma unroll
                for (int d = 0; d < 4; ++d) {
                    int row = mt * 16 + lg * 4 + d;
                    float v = acc[g][mt][nt][d] + bb;
                    float gl = gelu_tanh(v);
                    msum += swin[g][row] ? gl : 0.f;
                }
            msum += __shfl_xor(msum, 16);
            msum += __shfl_xor(msum, 32);
            if (lg == 0) {
                float inv = 1.0f / (float)max(ncnt[s0 + g], 1);
                mh[(size_t)(s0 + g) * 256 + col] = msum * inv;
            }
        }
    }
}

// ---- f32 GEMM (used for final out = mh@W2 + (cnt>0)*b2): C[M x 256] = A[M x 256]@B[256 x 256] ----
__global__ void gemm64_kernel(const float* __restrict__ A, const int* __restrict__ rowidx,
                              const float* __restrict__ B, const float* __restrict__ bias,
                              const int* __restrict__ ncnt, float* __restrict__ C, int ldc) {
    __shared__ float At[32][68];
    __shared__ float Bs[32][64];
    int tid = threadIdx.x;
    int rb = blockIdx.x * 64, cb = blockIdx.y * 64;
    int tx = tid & 15, ty = tid >> 4;
    float acc[4][4] = {};
    int lr = tid >> 2, kg = tid & 3;
    int arow = rowidx ? rowidx[rb + lr] : (rb + lr);
    const float* aptr = A + (size_t)arow * 256 + kg * 8;
    int k2 = tid >> 3, cg = tid & 7;
    const float* bptr = B + (size_t)k2 * 256 + cb + cg * 8;
    for (int kc = 0; kc < 256; kc += 32) {
        float4 a0 = *(const float4*)(aptr + kc);
        float4 a1 = *(const float4*)(aptr + kc + 4);
        float4 b0 = *(const float4*)(bptr + (size_t)kc * 256);
        float4 b1v = *(const float4*)(bptr + (size_t)kc * 256 + 4);
        At[kg * 8 + 0][lr] = a0.x; At[kg * 8 + 1][lr] = a0.y;
        At[kg * 8 + 2][lr] = a0.z; At[kg * 8 + 3][lr] = a0.w;
        At[kg * 8 + 4][lr] = a1.x; At[kg * 8 + 5][lr] = a1.y;
        At[kg * 8 + 6][lr] = a1.z; At[kg * 8 + 7][lr] = a1.w;
        *(float4*)&Bs[k2][cg * 8]     = b0;
        *(float4*)&Bs[k2][cg * 8 + 4] = b1v;
        __syncthreads();
#pragma unroll
        for (int k = 0; k < 32; ++k) {
            float4 av = *(const float4*)&At[k][ty * 4];
            float4 bv = *(const float4*)&Bs[k][tx * 4];
            float a[4] = {av.x, av.y, av.z, av.w};
            float bb[4] = {bv.x, bv.y, bv.z, bv.w};
#pragma unroll
            for (int i = 0; i < 4; ++i)
#pragma unroll
                for (int j = 0; j < 4; ++j)
                    acc[i][j] = fmaf(a[i], bb[j], acc[i][j]);
        }
        __syncthreads();
    }
#pragma unroll
    for (int i = 0; i < 4; ++i) {
        int row = rb + ty * 4 + i;
        float bv[4] = {0.f, 0.f, 0.f, 0.f};
        if (bias) {
            float sc = ncnt ? ((ncnt[row] > 0) ? 1.0f : 0.0f) : 1.0f;
#pragma unroll
            for (int j = 0; j < 4; ++j) bv[j] = sc * bias[cb + tx * 4 + j];
        }
        float4 o;
        o.x = acc[i][0] + bv[0]; o.y = acc[i][1] + bv[1];
        o.z = acc[i][2] + bv[2]; o.w = acc[i][3] + bv[3];
        *(float4*)(C + (size_t)row * ldc + cb + tx * 4) = o;
    }
}

extern "C" void kernel_launch(void* const* d_in, const int* in_sizes, int n_in,
                              void* d_out, int out_size, void* d_ws, size_t ws_size,
                              hipStream_t stream) {
    const float* feat  = (const float*)d_in[0];
    const float* pos   = (const float*)d_in[1];
    const int*   sup   = (const int*)d_in[2];
    const float* projW = (const float*)d_in[4];
    const float* projb = (const float*)d_in[5];
    const float* W1    = (const float*)d_in[6];
    const float* b1    = (const float*)d_in[7];
    const float* W2    = (const float*)d_in[8];
    const float* b2    = (const float*)d_in[9];
    float* out = (float*)d_out;

    char* p = (char*)d_ws;
    auto alloc = [&](size_t bytes) { char* q = p; p += (bytes + 255) & ~255ULL; return q; };
    __hip_bfloat16* xb  = (__hip_bfloat16*)alloc((size_t)N_NODES * HDIM * 2);  // 33.6 MB
    __hip_bfloat16* w1f = (__hip_bfloat16*)alloc((size_t)256 * 512 * 2);       // 256 KB frag-ordered
    float* mh     = (float*)alloc((size_t)S_SUP * HDIM * 4);
    int*   sidx   = (int*)alloc((size_t)N_NODES * 4);
    float* spos   = (float*)alloc((size_t)N_NODES * 4);
    int*   nbr    = (int*)alloc((size_t)S_SUP * KNN * 4);
    int*   within = (int*)alloc((size_t)S_SUP * KNN * 4);
    int*   ncnt   = (int*)alloc((size_t)S_SUP * 4);
    int*   bin_cnt = (int*)alloc((size_t)NBINS * 4);
    int*   cursor  = (int*)alloc((size_t)NBINS * 4);
    int*   bin_ofs = (int*)alloc((size_t)(NBINS + 1) * 4);

    // Workspace guard (~38 MB needed): never write OOB — fail cleanly instead.
    size_t needed = (size_t)(p - (char*)d_ws);
    if (needed > ws_size) {
        hipMemsetAsync(d_out, 0, (size_t)out_size * 4, stream);
        return;
    }

    hipMemsetAsync(bin_cnt, 0, (size_t)NBINS * 4, stream);
    embed_kernel<<<N_NODES / 64, 256, 0, stream>>>(feat, pos, projW, projb, xb);
    transpose_w1_kernel<<<256, 256, 0, stream>>>(W1, w1f);
    hist_kernel<<<N_NODES / 256, 256, 0, stream>>>(pos, bin_cnt);
    scan_kernel<<<1, 1024, 0, stream>>>(bin_cnt, bin_ofs, cursor);
    scatter_kernel<<<N_NODES / 256, 256, 0, stream>>>(pos, cursor, sidx, spos);
    topk_kernel<<<S_SUP, 64, 0, stream>>>(pos, sup, bin_ofs, sidx, spos, nbr, within, ncnt);
    edge_mlp_pool_kernel<<<S_SUP / GSUP, 256, 0, stream>>>(xb, w1f, b1, sup, nbr, within, ncnt, mh);
    gemm64_kernel<<<dim3(S_SUP / 64, 4), 256, 0, stream>>>(mh, nullptr, W2, b2, ncnt, out, 256);
}

// Round 14
// 211.731 us; speedup vs baseline: 1.8840x; 1.0336x over previous
//
#include <hip/hip_runtime.h>
#include <hip/hip_bf16.h>
#include <float.h>

#define N_NODES 65536
#define S_SUP   2048
#define HDIM    256
#define KNN     32
#define NBINS   4096
#define CAP     4096

typedef __attribute__((ext_vector_type(8))) __bf16 bf16x8;
typedef __attribute__((ext_vector_type(4))) float  f32x4;

// ---------------- node embedding: xb = bf16(feat@projW + projb + sincos(pos)) ----------------
__global__ __launch_bounds__(256) void embed_kernel(
        const float* __restrict__ feat, const float* __restrict__ pos,
        const float* __restrict__ W, const float* __restrict__ b,
        __hip_bfloat16* __restrict__ xb) {
    __shared__ float sf[64][32];    // feat tile (8 KB)
    __shared__ float sp[64];
    int tid = threadIdx.x;
    int rb = blockIdx.x * 64;
    {
        int r = tid >> 2, kg = tid & 3;
        const float* src = feat + (size_t)(rb + r) * 32 + kg * 8;
        float4 v0 = *(const float4*)(src);
        float4 v1 = *(const float4*)(src + 4);
        *(float4*)&sf[r][kg * 8]     = v0;
        *(float4*)&sf[r][kg * 8 + 4] = v1;
    }
    if (tid < 64) sp[tid] = pos[rb + tid];
    int c = tid;
    float wcol[32];
#pragma unroll
    for (int k = 0; k < 32; ++k) wcol[k] = W[k * 256 + c];   // coalesced, L2-hot
    float bias = b[c];
    const float coef = -logf(10000.0f) / 127.0f;
    float fr = expf((float)(c & 127) * coef);
    bool is_sin = (c < 128);
    __syncthreads();
    for (int r = 0; r < 64; ++r) {
        float acc = bias;
#pragma unroll
        for (int k = 0; k < 32; ++k) acc = fmaf(sf[r][k], wcol[k], acc);
        float e = sp[r] * fr;
        acc += is_sin ? __sinf(e) : __cosf(e);
        xb[(size_t)(rb + r) * 256 + c] = __float2bfloat16(acc);
    }
}

// ---- W1 -> MFMA-fragment-ordered bf16 layout:
//      w1f[((ks*16 + ntg)*64 + lane)*8 + e] = W1[k][n],
//      n = ntg*16 + (lane&15), k = ks*32 + (lane>>4)*8 + e   (ks 0..15 covers K=512)
//      A wave's B-fragment load becomes base + lane*16B: fully coalesced. ----
__global__ void transpose_w1_kernel(const float* __restrict__ W1, __hip_bfloat16* __restrict__ w1f) {
    int tile = blockIdx.x;            // 0..255 : ks = tile>>4, ntg = tile&15
    int ks = tile >> 4, ntg = tile & 15;
    int tid = threadIdx.x;
    for (int i = tid; i < 512; i += 256) {
        int l = i >> 3, e = i & 7;
        int n = ntg * 16 + (l & 15);
        int k = ks * 32 + ((l >> 4) << 3) + e;
        w1f[(size_t)tile * 512 + i] = __float2bfloat16(W1[(size_t)k * 256 + n]);
    }
}

// ---------------- binning (counting sort by position) ----------------
__device__ __forceinline__ int pos_bin(float p) {
    int b = (int)(p * (float)NBINS);
    return min(max(b, 0), NBINS - 1);
}

__global__ void hist_kernel(const float* __restrict__ pos, int* __restrict__ bin_cnt) {
    int n = blockIdx.x * blockDim.x + threadIdx.x;
    atomicAdd(&bin_cnt[pos_bin(pos[n])], 1);
}

__global__ void scan_kernel(const int* __restrict__ bin_cnt, int* __restrict__ bin_ofs,
                            int* __restrict__ cursor) {
    __shared__ int sdata[1024];
    int t = threadIdx.x;
    int v[4]; int s = 0;
#pragma unroll
    for (int i = 0; i < 4; ++i) { v[i] = bin_cnt[t * 4 + i]; s += v[i]; }
    sdata[t] = s;
    __syncthreads();
    for (int off = 1; off < 1024; off <<= 1) {
        int add = (t >= off) ? sdata[t - off] : 0;
        __syncthreads();
        sdata[t] += add;
        __syncthreads();
    }
    int run = sdata[t] - s;   // exclusive prefix
#pragma unroll
    for (int i = 0; i < 4; ++i) {
        bin_ofs[t * 4 + i] = run;
        cursor[t * 4 + i]  = run;
        run += v[i];
    }
    if (t == 1023) bin_ofs[NBINS] = run;
}

__global__ void scatter_kernel(const float* __restrict__ pos, int* __restrict__ cursor,
                               int* __restrict__ sidx, float* __restrict__ spos) {
    int n = blockIdx.x * blockDim.x + threadIdx.x;
    float p = pos[n];
    int b = pos_bin(p);
    int dst = atomicAdd(&cursor[b], 1);
    sidx[dst] = n;
    spos[dst] = p;
}

// ---------------- exact top-32 nearest per supernode (1 wave / supernode) ----------------
__global__ void topk_kernel(const float* __restrict__ pos, const int* __restrict__ sup,
                            const int* __restrict__ bin_ofs, const int* __restrict__ sidx,
                            const float* __restrict__ spos,
                            int* __restrict__ nbr, int* __restrict__ within,
                            int* __restrict__ ncnt) {
    __shared__ float cd2[CAP];
    __shared__ int   cidx[CAP];
    __shared__ float rd2[KNN];
    __shared__ int   ridx[KNN];
    int s = blockIdx.x;
    int lane = threadIdx.x;
    float p = pos[sup[s]];
    int hb = pos_bin(p);
    const float BINW = 1.0f / (float)NBINS;
    int ccnt = 0;
    for (int r = 2;; r <<= 1) {
        int lo = max(hb - r, 0), hi = min(hb + r, NBINS - 1);
        int start = bin_ofs[lo], end = bin_ofs[hi + 1];
        ccnt = min(end - start, CAP);
        for (int i = lane; i < ccnt; i += 64) {
            float pp = spos[start + i];
            float d = p - pp;
            cd2[i] = d * d;
            cidx[i] = sidx[start + i];
        }
        __syncthreads();
        float gl = (lo == 0) ? FLT_MAX : (p - (float)lo * BINW);
        float gr = (hi == NBINS - 1) ? FLT_MAX : ((float)(hi + 1) * BINW - p);
        float g = fminf(gl, gr);
        float g2 = (g >= FLT_MAX) ? FLT_MAX : (g * 0.999f) * (g * 0.999f);
        int cw = 0;
        for (int i = lane; i < ccnt; i += 64) cw += (cd2[i] < g2) ? 1 : 0;
        for (int o = 32; o; o >>= 1) cw += __shfl_xor(cw, o);
        if (cw >= KNN || (lo == 0 && hi == NBINS - 1)) break;
        __syncthreads();
    }
    for (int t = 0; t < KNN; ++t) {
        unsigned long long best = ~0ULL;
        int bslot = -1;
        for (int i = lane; i < ccnt; i += 64) {
            unsigned long long k =
                ((unsigned long long)__float_as_uint(cd2[i]) << 32) | (unsigned)cidx[i];
            if (k < best) { best = k; bslot = i; }
        }
        unsigned long long mybest = best;
        for (int o = 32; o; o >>= 1) {
            unsigned long long other = __shfl_xor(best, o);
            best = best < other ? best : other;
        }
        if (mybest == best && bslot >= 0) cd2[bslot] = FLT_MAX;
        if (lane == 0) {
            rd2[t]  = __uint_as_float((unsigned)(best >> 32));
            ridx[t] = (int)(unsigned)(best & 0xffffffffULL);
        }
        __syncthreads();
    }
    const float R2 = (float)(0.005 * 0.005);
    if (lane < KNN) {
        float d2v = rd2[lane];
        int w = (d2v <= R2) ? 1 : 0;
        nbr[s * KNN + lane] = ridx[lane];
        within[s * KNN + lane] = w;
        unsigned long long m = __ballot(w != 0);
        int cnt = __popcll(m & 0xffffffffULL);
        if (lane == 0) ncnt[s] = cnt;
    }
}

// ---- fast gelu (tanh approx): 0.5v(1+tanh(u)) == v*sigmoid(2u), u=0.79788456(v+0.044715v^3)
//      exp(-2u) path is NaN-safe at both extremes (v->+inf: e->0, g->v; v->-inf: e->inf, rcp->0, g->0)
__device__ __forceinline__ float gelu_fast(float v) {
    float u = 0.7978845608028654f * (v + 0.044715f * v * v * v);
    float e = __expf(-2.0f * u);
    return v * __builtin_amdgcn_rcpf(1.0f + e);
}

// ---- fused per-supernode edge MLP + pool, 1 supernode per block, frag-ordered B:
//      mh[s] = mean_{j in-radius} gelu( concat(x[nbr_j], x[sup_s]) @ W1 + b1 )
//      32 VGPR acc -> high occupancy; 2048 blocks for TLP. ----
__global__ __launch_bounds__(256) void edge_mlp_pool_kernel(
        const __hip_bfloat16* __restrict__ xb_,   // [65536][256]
        const __hip_bfloat16* __restrict__ w1f_,  // frag-ordered [16 ks][16 ntg][64 lane][8 e]
        const float* __restrict__ b1,
        const int* __restrict__ sup,
        const int* __restrict__ nbr, const int* __restrict__ within,
        const int* __restrict__ ncnt, float* __restrict__ mh) {
    const ushort* xb  = (const ushort*)xb_;
    const ushort* w1f = (const ushort*)w1f_;
    int s = blockIdx.x;
    int tid = threadIdx.x;
    int l = tid & 63, w = tid >> 6;
    int lr = l & 15, lg = l >> 4;
    __shared__ int snbr[KNN];
    __shared__ int swin[KNN];
    if (tid < KNN) { snbr[tid] = nbr[s * KNN + tid]; swin[tid] = within[s * KNN + tid]; }
    __syncthreads();
    // A row pointers (m89-verified layout: A row=lane&15, k=(lane>>4)*8+e)
    const ushort* ar0 = xb + (size_t)snbr[lr]      * 256;
    const ushort* ar1 = xb + (size_t)snbr[16 + lr] * 256;
    const ushort* asp = xb + (size_t)sup[s]        * 256;
    int koff = lg * 8;
    f32x4 acc[2][4] = {};
    // low K half (ks 0..7): k in [0,256) -> x[nbr]
#pragma unroll 1
    for (int ks = 0; ks < 8; ++ks) {
        int k = ks * 32 + koff;
        bf16x8 bfr[4];
#pragma unroll
        for (int nt = 0; nt < 4; ++nt)
            bfr[nt] = *(const bf16x8*)(w1f + ((size_t)(ks * 16 + w * 4 + nt) * 64 + l) * 8);
        bf16x8 a0 = *(const bf16x8*)(ar0 + k);
        bf16x8 a1 = *(const bf16x8*)(ar1 + k);
#pragma unroll
        for (int nt = 0; nt < 4; ++nt) {
            acc[0][nt] = __builtin_amdgcn_mfma_f32_16x16x32_bf16(a0, bfr[nt], acc[0][nt], 0, 0, 0);
            acc[1][nt] = __builtin_amdgcn_mfma_f32_16x16x32_bf16(a1, bfr[nt], acc[1][nt], 0, 0, 0);
        }
    }
    // high K half (ks 8..15): virtual k in [256,512) -> x[sup] (same A for both M tiles)
#pragma unroll 1
    for (int ks = 8; ks < 16; ++ks) {
        int k = (ks - 8) * 32 + koff;
        bf16x8 bfr[4];
#pragma unroll
        for (int nt = 0; nt < 4; ++nt)
            bfr[nt] = *(const bf16x8*)(w1f + ((size_t)(ks * 16 + w * 4 + nt) * 64 + l) * 8);
        bf16x8 a = *(const bf16x8*)(asp + k);
#pragma unroll
        for (int nt = 0; nt < 4; ++nt) {
            acc[0][nt] = __builtin_amdgcn_mfma_f32_16x16x32_bf16(a, bfr[nt], acc[0][nt], 0, 0, 0);
            acc[1][nt] = __builtin_amdgcn_mfma_f32_16x16x32_bf16(a, bfr[nt], acc[1][nt], 0, 0, 0);
        }
    }
    // epilogue: D lane holds row (mt*16 + lg*4 + d), col (w*64 + nt*16 + lr)
    float inv = 1.0f / (float)max(ncnt[s], 1);
#pragma unroll
    for (int nt = 0; nt < 4; ++nt) {
        int col = w * 64 + nt * 16 + lr;
        float bb = b1[col];
        float msum = 0.f;
#pragma unroll
        for (int mt = 0; mt < 2; ++mt)
#pragma unroll
            for (int d = 0; d < 4; ++d) {
                int row = mt * 16 + lg * 4 + d;
                float v = acc[mt][nt][d] + bb;
                float g = gelu_fast(v);
                msum += swin[row] ? g : 0.f;
            }
        msum += __shfl_xor(msum, 16);
        msum += __shfl_xor(msum, 32);
        if (lg == 0) mh[(size_t)s * 256 + col] = msum * inv;
    }
}

// ---- f32 GEMM (used for final out = mh@W2 + (cnt>0)*b2): C[M x 256] = A[M x 256]@B[256 x 256] ----
__global__ void gemm64_kernel(const float* __restrict__ A, const int* __restrict__ rowidx,
                              const float* __restrict__ B, const float* __restrict__ bias,
                              const int* __restrict__ ncnt, float* __restrict__ C, int ldc) {
    __shared__ float At[32][68];
    __shared__ float Bs[32][64];
    int tid = threadIdx.x;
    int rb = blockIdx.x * 64, cb = blockIdx.y * 64;
    int tx = tid & 15, ty = tid >> 4;
    float acc[4][4] = {};
    int lr = tid >> 2, kg = tid & 3;
    int arow = rowidx ? rowidx[rb + lr] : (rb + lr);
    const float* aptr = A + (size_t)arow * 256 + kg * 8;
    int k2 = tid >> 3, cg = tid & 7;
    const float* bptr = B + (size_t)k2 * 256 + cb + cg * 8;
    for (int kc = 0; kc < 256; kc += 32) {
        float4 a0 = *(const float4*)(aptr + kc);
        float4 a1 = *(const float4*)(aptr + kc + 4);
        float4 b0 = *(const float4*)(bptr + (size_t)kc * 256);
        float4 b1v = *(const float4*)(bptr + (size_t)kc * 256 + 4);
        At[kg * 8 + 0][lr] = a0.x; At[kg * 8 + 1][lr] = a0.y;
        At[kg * 8 + 2][lr] = a0.z; At[kg * 8 + 3][lr] = a0.w;
        At[kg * 8 + 4][lr] = a1.x; At[kg * 8 + 5][lr] = a1.y;
        At[kg * 8 + 6][lr] = a1.z; At[kg * 8 + 7][lr] = a1.w;
        *(float4*)&Bs[k2][cg * 8]     = b0;
        *(float4*)&Bs[k2][cg * 8 + 4] = b1v;
        __syncthreads();
#pragma unroll
        for (int k = 0; k < 32; ++k) {
            float4 av = *(const float4*)&At[k][ty * 4];
            float4 bv = *(const float4*)&Bs[k][tx * 4];
            float a[4] = {av.x, av.y, av.z, av.w};
            float bb[4] = {bv.x, bv.y, bv.z, bv.w};
#pragma unroll
            for (int i = 0; i < 4; ++i)
#pragma unroll
                for (int j = 0; j < 4; ++j)
                    acc[i][j] = fmaf(a[i], bb[j], acc[i][j]);
        }
        __syncthreads();
    }
#pragma unroll
    for (int i = 0; i < 4; ++i) {
        int row = rb + ty * 4 + i;
        float bv[4] = {0.f, 0.f, 0.f, 0.f};
        if (bias) {
            float sc = ncnt ? ((ncnt[row] > 0) ? 1.0f : 0.0f) : 1.0f;
#pragma unroll
            for (int j = 0; j < 4; ++j) bv[j] = sc * bias[cb + tx * 4 + j];
        }
        float4 o;
        o.x = acc[i][0] + bv[0]; o.y = acc[i][1] + bv[1];
        o.z = acc[i][2] + bv[2]; o.w = acc[i][3] + bv[3];
        *(float4*)(C + (size_t)row * ldc + cb + tx * 4) = o;
    }
}

extern "C" void kernel_launch(void* const* d_in, const int* in_sizes, int n_in,
                              void* d_out, int out_size, void* d_ws, size_t ws_size,
                              hipStream_t stream) {
    const float* feat  = (const float*)d_in[0];
    const float* pos   = (const float*)d_in[1];
    const int*   sup   = (const int*)d_in[2];
    const float* projW = (const float*)d_in[4];
    const float* projb = (const float*)d_in[5];
    const float* W1    = (const float*)d_in[6];
    const float* b1    = (const float*)d_in[7];
    const float* W2    = (const float*)d_in[8];
    const float* b2    = (const float*)d_in[9];
    float* out = (float*)d_out;

    char* p = (char*)d_ws;
    auto alloc = [&](size_t bytes) { char* q = p; p += (bytes + 255) & ~255ULL; return q; };
    __hip_bfloat16* xb  = (__hip_bfloat16*)alloc((size_t)N_NODES * HDIM * 2);  // 33.6 MB
    __hip_bfloat16* w1f = (__hip_bfloat16*)alloc((size_t)256 * 512 * 2);       // 256 KB frag-ordered
    float* mh     = (float*)alloc((size_t)S_SUP * HDIM * 4);
    int*   sidx   = (int*)alloc((size_t)N_NODES * 4);
    float* spos   = (float*)alloc((size_t)N_NODES * 4);
    int*   nbr    = (int*)alloc((size_t)S_SUP * KNN * 4);
    int*   within = (int*)alloc((size_t)S_SUP * KNN * 4);
    int*   ncnt   = (int*)alloc((size_t)S_SUP * 4);
    int*   bin_cnt = (int*)alloc((size_t)NBINS * 4);
    int*   cursor  = (int*)alloc((size_t)NBINS * 4);
    int*   bin_ofs = (int*)alloc((size_t)(NBINS + 1) * 4);

    // Workspace guard (~38 MB needed): never write OOB — fail cleanly instead.
    size_t needed = (size_t)(p - (char*)d_ws);
    if (needed > ws_size) {
        hipMemsetAsync(d_out, 0, (size_t)out_size * 4, stream);
        return;
    }

    hipMemsetAsync(bin_cnt, 0, (size_t)NBINS * 4, stream);
    embed_kernel<<<N_NODES / 64, 256, 0, stream>>>(feat, pos, projW, projb, xb);
    transpose_w1_kernel<<<256, 256, 0, stream>>>(W1, w1f);
    hist_kernel<<<N_NODES / 256, 256, 0, stream>>>(pos, bin_cnt);
    scan_kernel<<<1, 1024, 0, stream>>>(bin_cnt, bin_ofs, cursor);
    scatter_kernel<<<N_NODES / 256, 256, 0, stream>>>(pos, cursor, sidx, spos);
    topk_kernel<<<S_SUP, 64, 0, stream>>>(pos, sup, bin_ofs, sidx, spos, nbr, within, ncnt);
    edge_mlp_pool_kernel<<<S_SUP, 256, 0, stream>>>(xb, w1f, b1, sup, nbr, within, ncnt, mh);
    gemm64_kernel<<<dim3(S_SUP / 64, 4), 256, 0, stream>>>(mh, nullptr, W2, b2, ncnt, out, 256);
}

// Round 15
// 201.707 us; speedup vs baseline: 1.9776x; 1.0497x over previous
//
#include <hip/hip_runtime.h>
#include <hip/hip_bf16.h>
#include <float.h>

#define N_NODES 65536
#define S_SUP   2048
#define HDIM    256
#define KNN     32
#define NBINS   4096
#define CAP     4096
#define GSUP    2

typedef __attribute__((ext_vector_type(8))) __bf16 bf16x8;
typedef __attribute__((ext_vector_type(4))) float  f32x4;

// ---------------- node embedding: xb = bf16(feat@projW + projb + sincos(pos)) ----------------
__global__ __launch_bounds__(256) void embed_kernel(
        const float* __restrict__ feat, const float* __restrict__ pos,
        const float* __restrict__ W, const float* __restrict__ b,
        __hip_bfloat16* __restrict__ xb) {
    __shared__ float sf[64][32];    // feat tile (8 KB)
    __shared__ float sp[64];
    int tid = threadIdx.x;
    int rb = blockIdx.x * 64;
    {
        int r = tid >> 2, kg = tid & 3;
        const float* src = feat + (size_t)(rb + r) * 32 + kg * 8;
        float4 v0 = *(const float4*)(src);
        float4 v1 = *(const float4*)(src + 4);
        *(float4*)&sf[r][kg * 8]     = v0;
        *(float4*)&sf[r][kg * 8 + 4] = v1;
    }
    if (tid < 64) sp[tid] = pos[rb + tid];
    int c = tid;
    float wcol[32];
#pragma unroll
    for (int k = 0; k < 32; ++k) wcol[k] = W[k * 256 + c];   // coalesced, L2-hot
    float bias = b[c];
    const float coef = -logf(10000.0f) / 127.0f;
    float fr = expf((float)(c & 127) * coef);
    bool is_sin = (c < 128);
    __syncthreads();
    for (int r = 0; r < 64; ++r) {
        float acc = bias;
#pragma unroll
        for (int k = 0; k < 32; ++k) acc = fmaf(sf[r][k], wcol[k], acc);
        float e = sp[r] * fr;
        acc += is_sin ? __sinf(e) : __cosf(e);
        xb[(size_t)(rb + r) * 256 + c] = __float2bfloat16(acc);
    }
}

// ---- W1/W2 -> MFMA-fragment-ordered bf16 layouts:
//      wf[((ks*16 + ntg)*64 + lane)*8 + e] = W[k][n],
//      n = ntg*16 + (lane&15), k = ks*32 + (lane>>4)*8 + e
//      W1: 16 ks-tiles (K=512, tiles 0..255); W2: 8 ks-tiles (K=256, tiles 256..383). ----
__global__ void transpose_w_kernel(const float* __restrict__ W1, const float* __restrict__ W2,
                                   __hip_bfloat16* __restrict__ w1f, __hip_bfloat16* __restrict__ w2f) {
    int tile = blockIdx.x;
    int tid = threadIdx.x;
    const float* W = (tile < 256) ? W1 : W2;
    __hip_bfloat16* dst = (tile < 256) ? w1f : w2f;
    int t = (tile < 256) ? tile : (tile - 256);
    int ks = t >> 4, ntg = t & 15;
    for (int i = tid; i < 512; i += 256) {
        int l = i >> 3, e = i & 7;
        int n = ntg * 16 + (l & 15);
        int k = ks * 32 + ((l >> 4) << 3) + e;
        dst[(size_t)t * 512 + i] = __float2bfloat16(W[(size_t)k * 256 + n]);
    }
}

// ---------------- binning (counting sort by position) ----------------
__device__ __forceinline__ int pos_bin(float p) {
    int b = (int)(p * (float)NBINS);
    return min(max(b, 0), NBINS - 1);
}

__global__ void hist_kernel(const float* __restrict__ pos, int* __restrict__ bin_cnt) {
    int n = blockIdx.x * blockDim.x + threadIdx.x;
    atomicAdd(&bin_cnt[pos_bin(pos[n])], 1);
}

__global__ void scan_kernel(const int* __restrict__ bin_cnt, int* __restrict__ bin_ofs,
                            int* __restrict__ cursor) {
    __shared__ int sdata[1024];
    int t = threadIdx.x;
    int v[4]; int s = 0;
#pragma unroll
    for (int i = 0; i < 4; ++i) { v[i] = bin_cnt[t * 4 + i]; s += v[i]; }
    sdata[t] = s;
    __syncthreads();
    for (int off = 1; off < 1024; off <<= 1) {
        int add = (t >= off) ? sdata[t - off] : 0;
        __syncthreads();
        sdata[t] += add;
        __syncthreads();
    }
    int run = sdata[t] - s;   // exclusive prefix
#pragma unroll
    for (int i = 0; i < 4; ++i) {
        bin_ofs[t * 4 + i] = run;
        cursor[t * 4 + i]  = run;
        run += v[i];
    }
    if (t == 1023) bin_ofs[NBINS] = run;
}

__global__ void scatter_kernel(const float* __restrict__ pos, int* __restrict__ cursor,
                               int* __restrict__ sidx, float* __restrict__ spos) {
    int n = blockIdx.x * blockDim.x + threadIdx.x;
    float p = pos[n];
    int b = pos_bin(p);
    int dst = atomicAdd(&cursor[b], 1);
    sidx[dst] = n;
    spos[dst] = p;
}

// ---------------- exact top-32 nearest per supernode (1 wave / supernode) ----------------
__global__ void topk_kernel(const float* __restrict__ pos, const int* __restrict__ sup,
                            const int* __restrict__ bin_ofs, const int* __restrict__ sidx,
                            const float* __restrict__ spos,
                            int* __restrict__ nbr, int* __restrict__ within,
                            int* __restrict__ ncnt) {
    __shared__ float cd2[CAP];
    __shared__ int   cidx[CAP];
    __shared__ float rd2[KNN];
    __shared__ int   ridx[KNN];
    int s = blockIdx.x;
    int lane = threadIdx.x;
    float p = pos[sup[s]];
    int hb = pos_bin(p);
    const float BINW = 1.0f / (float)NBINS;
    int ccnt = 0;
    for (int r = 2;; r <<= 1) {
        int lo = max(hb - r, 0), hi = min(hb + r, NBINS - 1);
        int start = bin_ofs[lo], end = bin_ofs[hi + 1];
        ccnt = min(end - start, CAP);
        for (int i = lane; i < ccnt; i += 64) {
            float pp = spos[start + i];
            float d = p - pp;
            cd2[i] = d * d;
            cidx[i] = sidx[start + i];
        }
        __syncthreads();
        float gl = (lo == 0) ? FLT_MAX : (p - (float)lo * BINW);
        float gr = (hi == NBINS - 1) ? FLT_MAX : ((float)(hi + 1) * BINW - p);
        float g = fminf(gl, gr);
        float g2 = (g >= FLT_MAX) ? FLT_MAX : (g * 0.999f) * (g * 0.999f);
        int cw = 0;
        for (int i = lane; i < ccnt; i += 64) cw += (cd2[i] < g2) ? 1 : 0;
        for (int o = 32; o; o >>= 1) cw += __shfl_xor(cw, o);
        if (cw >= KNN || (lo == 0 && hi == NBINS - 1)) break;
        __syncthreads();
    }
    for (int t = 0; t < KNN; ++t) {
        unsigned long long best = ~0ULL;
        int bslot = -1;
        for (int i = lane; i < ccnt; i += 64) {
            unsigned long long k =
                ((unsigned long long)__float_as_uint(cd2[i]) << 32) | (unsigned)cidx[i];
            if (k < best) { best = k; bslot = i; }
        }
        unsigned long long mybest = best;
        for (int o = 32; o; o >>= 1) {
            unsigned long long other = __shfl_xor(best, o);
            best = best < other ? best : other;
        }
        if (mybest == best && bslot >= 0) cd2[bslot] = FLT_MAX;
        if (lane == 0) {
            rd2[t]  = __uint_as_float((unsigned)(best >> 32));
            ridx[t] = (int)(unsigned)(best & 0xffffffffULL);
        }
        __syncthreads();
    }
    const float R2 = (float)(0.005 * 0.005);
    if (lane < KNN) {
        float d2v = rd2[lane];
        int w = (d2v <= R2) ? 1 : 0;
        nbr[s * KNN + lane] = ridx[lane];
        within[s * KNN + lane] = w;
        unsigned long long m = __ballot(w != 0);
        int cnt = __popcll(m & 0xffffffffULL);
        if (lane == 0) ncnt[s] = cnt;
    }
}

// ---- fast gelu (tanh approx): 0.5v(1+tanh(u)) == v*sigmoid(2u), u=0.79788456(v+0.044715v^3)
__device__ __forceinline__ float gelu_fast(float v) {
    float u = 0.7978845608028654f * (v + 0.044715f * v * v * v);
    float e = __expf(-2.0f * u);
    return v * __builtin_amdgcn_rcpf(1.0f + e);
}

// ---- fused per-supernode edge MLP + pool, G=2 supernodes per block, frag-ordered B:
//      mhb[s] = bf16( mean_{j in-radius} gelu( concat(x[nbr_j], x[sup_s]) @ W1 + b1 ) ) ----
__global__ __launch_bounds__(256) void edge_mlp_pool_kernel(
        const __hip_bfloat16* __restrict__ xb_,   // [65536][256]
        const __hip_bfloat16* __restrict__ w1f_,  // frag-ordered [16 ks][16 ntg][64 lane][8 e]
        const float* __restrict__ b1,
        const int* __restrict__ sup,
        const int* __restrict__ nbr, const int* __restrict__ within,
        const int* __restrict__ ncnt, __hip_bfloat16* __restrict__ mhb) {
    const ushort* xb  = (const ushort*)xb_;
    const ushort* w1f = (const ushort*)w1f_;
    int s0 = blockIdx.x * GSUP;
    int tid = threadIdx.x;
    int l = tid & 63, w = tid >> 6;
    int lr = l & 15, lg = l >> 4;
    __shared__ int snbr[GSUP][KNN];
    __shared__ int swin[GSUP][KNN];
    __shared__ int ssup[GSUP];
    if (tid < GSUP * KNN) {
        int g = tid >> 5, j = tid & 31;
        snbr[g][j] = nbr[(s0 + g) * KNN + j];
        swin[g][j] = within[(s0 + g) * KNN + j];
    }
    if (tid < GSUP) ssup[tid] = sup[s0 + tid];
    __syncthreads();
    // A row pointers (m89-verified layout: A row=lane&15, k=(lane>>4)*8+e)
    const ushort* ar0[GSUP];
    const ushort* ar1[GSUP];
    const ushort* asp[GSUP];
#pragma unroll
    for (int g = 0; g < GSUP; ++g) {
        ar0[g] = xb + (size_t)snbr[g][lr]      * 256;
        ar1[g] = xb + (size_t)snbr[g][16 + lr] * 256;
        asp[g] = xb + (size_t)ssup[g]          * 256;
    }
    int koff = lg * 8;
    f32x4 acc[GSUP][2][4] = {};
    // low K half (ks 0..7): k in [0,256) -> x[nbr]
#pragma unroll 1
    for (int ks = 0; ks < 8; ++ks) {
        int k = ks * 32 + koff;
        bf16x8 bfr[4];
#pragma unroll
        for (int nt = 0; nt < 4; ++nt)
            bfr[nt] = *(const bf16x8*)(w1f + ((size_t)(ks * 16 + w * 4 + nt) * 64 + l) * 8);
#pragma unroll
        for (int g = 0; g < GSUP; ++g) {
            bf16x8 a0 = *(const bf16x8*)(ar0[g] + k);
            bf16x8 a1 = *(const bf16x8*)(ar1[g] + k);
#pragma unroll
            for (int nt = 0; nt < 4; ++nt) {
                acc[g][0][nt] = __builtin_amdgcn_mfma_f32_16x16x32_bf16(a0, bfr[nt], acc[g][0][nt], 0, 0, 0);
                acc[g][1][nt] = __builtin_amdgcn_mfma_f32_16x16x32_bf16(a1, bfr[nt], acc[g][1][nt], 0, 0, 0);
            }
        }
    }
    // high K half (ks 8..15): virtual k in [256,512) -> x[sup] (same A for both M tiles)
#pragma unroll 1
    for (int ks = 8; ks < 16; ++ks) {
        int k = (ks - 8) * 32 + koff;
        bf16x8 bfr[4];
#pragma unroll
        for (int nt = 0; nt < 4; ++nt)
            bfr[nt] = *(const bf16x8*)(w1f + ((size_t)(ks * 16 + w * 4 + nt) * 64 + l) * 8);
#pragma unroll
        for (int g = 0; g < GSUP; ++g) {
            bf16x8 a = *(const bf16x8*)(asp[g] + k);
#pragma unroll
            for (int nt = 0; nt < 4; ++nt) {
                acc[g][0][nt] = __builtin_amdgcn_mfma_f32_16x16x32_bf16(a, bfr[nt], acc[g][0][nt], 0, 0, 0);
                acc[g][1][nt] = __builtin_amdgcn_mfma_f32_16x16x32_bf16(a, bfr[nt], acc[g][1][nt], 0, 0, 0);
            }
        }
    }
    // epilogue: D lane holds row (mt*16 + lg*4 + d), col (w*64 + nt*16 + lr)
#pragma unroll
    for (int nt = 0; nt < 4; ++nt) {
        int col = w * 64 + nt * 16 + lr;
        float bb = b1[col];
#pragma unroll
        for (int g = 0; g < GSUP; ++g) {
            float msum = 0.f;
#pragma unroll
            for (int mt = 0; mt < 2; ++mt)
#pragma unroll
                for (int d = 0; d < 4; ++d) {
                    int row = mt * 16 + lg * 4 + d;
                    float v = acc[g][mt][nt][d] + bb;
                    float gl = gelu_fast(v);
                    msum += swin[g][row] ? gl : 0.f;
                }
            msum += __shfl_xor(msum, 16);
            msum += __shfl_xor(msum, 32);
            if (lg == 0) {
                float inv = 1.0f / (float)max(ncnt[s0 + g], 1);
                mhb[(size_t)(s0 + g) * 256 + col] = __float2bfloat16(msum * inv);
            }
        }
    }
}

// ---- out = mhb @ W2 + (cnt>0)*b2 : bf16 MFMA, M=2048 (32/block), N=256, K=256 ----
__global__ __launch_bounds__(256) void out_gemm_kernel(
        const __hip_bfloat16* __restrict__ mhb_, const __hip_bfloat16* __restrict__ w2f_,
        const float* __restrict__ b2, const int* __restrict__ ncnt, float* __restrict__ out) {
    const ushort* mhb = (const ushort*)mhb_;
    const ushort* w2f = (const ushort*)w2f_;
    int rb = blockIdx.x * 32;
    int tid = threadIdx.x;
    int l = tid & 63, w = tid >> 6;
    int lr = l & 15, lg = l >> 4;
    const ushort* ar0 = mhb + (size_t)(rb + lr) * 256;
    const ushort* ar1 = mhb + (size_t)(rb + 16 + lr) * 256;
    int koff = lg * 8;
    f32x4 acc[2][4] = {};
#pragma unroll 1
    for (int ks = 0; ks < 8; ++ks) {
        int k = ks * 32 + koff;
        bf16x8 bfr[4];
#pragma unroll
        for (int nt = 0; nt < 4; ++nt)
            bfr[nt] = *(const bf16x8*)(w2f + ((size_t)(ks * 16 + w * 4 + nt) * 64 + l) * 8);
        bf16x8 a0 = *(const bf16x8*)(ar0 + k);
        bf16x8 a1 = *(const bf16x8*)(ar1 + k);
#pragma unroll
        for (int nt = 0; nt < 4; ++nt) {
            acc[0][nt] = __builtin_amdgcn_mfma_f32_16x16x32_bf16(a0, bfr[nt], acc[0][nt], 0, 0, 0);
            acc[1][nt] = __builtin_amdgcn_mfma_f32_16x16x32_bf16(a1, bfr[nt], acc[1][nt], 0, 0, 0);
        }
    }
#pragma unroll
    for (int nt = 0; nt < 4; ++nt) {
        int col = w * 64 + nt * 16 + lr;
        float bb = b2[col];
#pragma unroll
        for (int mt = 0; mt < 2; ++mt)
#pragma unroll
            for (int d = 0; d < 4; ++d) {
                int row = rb + mt * 16 + lg * 4 + d;
                float sc = (ncnt[row] > 0) ? 1.0f : 0.0f;
                out[(size_t)row * 256 + col] = acc[mt][nt][d] + sc * bb;
            }
    }
}

extern "C" void kernel_launch(void* const* d_in, const int* in_sizes, int n_in,
                              void* d_out, int out_size, void* d_ws, size_t ws_size,
                              hipStream_t stream) {
    const float* feat  = (const float*)d_in[0];
    const float* pos   = (const float*)d_in[1];
    const int*   sup   = (const int*)d_in[2];
    const float* projW = (const float*)d_in[4];
    const float* projb = (const float*)d_in[5];
    const float* W1    = (const float*)d_in[6];
    const float* b1    = (const float*)d_in[7];
    const float* W2    = (const float*)d_in[8];
    const float* b2    = (const float*)d_in[9];
    float* out = (float*)d_out;

    char* p = (char*)d_ws;
    auto alloc = [&](size_t bytes) { char* q = p; p += (bytes + 255) & ~255ULL; return q; };
    __hip_bfloat16* xb  = (__hip_bfloat16*)alloc((size_t)N_NODES * HDIM * 2);  // 33.6 MB
    __hip_bfloat16* w1f = (__hip_bfloat16*)alloc((size_t)256 * 512 * 2);       // 256 KB frag-ordered
    __hip_bfloat16* w2f = (__hip_bfloat16*)alloc((size_t)128 * 512 * 2);       // 128 KB frag-ordered
    __hip_bfloat16* mhb = (__hip_bfloat16*)alloc((size_t)S_SUP * HDIM * 2);    // 1 MB
    int*   sidx   = (int*)alloc((size_t)N_NODES * 4);
    float* spos   = (float*)alloc((size_t)N_NODES * 4);
    int*   nbr    = (int*)alloc((size_t)S_SUP * KNN * 4);
    int*   within = (int*)alloc((size_t)S_SUP * KNN * 4);
    int*   ncnt   = (int*)alloc((size_t)S_SUP * 4);
    int*   bin_cnt = (int*)alloc((size_t)NBINS * 4);
    int*   cursor  = (int*)alloc((size_t)NBINS * 4);
    int*   bin_ofs = (int*)alloc((size_t)(NBINS + 1) * 4);

    // Workspace guard (~36 MB needed): never write OOB — fail cleanly instead.
    size_t needed = (size_t)(p - (char*)d_ws);
    if (needed > ws_size) {
        hipMemsetAsync(d_out, 0, (size_t)out_size * 4, stream);
        return;
    }

    hipMemsetAsync(bin_cnt, 0, (size_t)NBINS * 4, stream);
    embed_kernel<<<N_NODES / 64, 256, 0, stream>>>(feat, pos, projW, projb, xb);
    transpose_w_kernel<<<384, 256, 0, stream>>>(W1, W2, w1f, w2f);
    hist_kernel<<<N_NODES / 256, 256, 0, stream>>>(pos, bin_cnt);
    scan_kernel<<<1, 1024, 0, stream>>>(bin_cnt, bin_ofs, cursor);
    scatter_kernel<<<N_NODES / 256, 256, 0, stream>>>(pos, cursor, sidx, spos);
    topk_kernel<<<S_SUP, 64, 0, stream>>>(pos, sup, bin_ofs, sidx, spos, nbr, within, ncnt);
    edge_mlp_pool_kernel<<<S_SUP / GSUP, 256, 0, stream>>>(xb, w1f, b1, sup, nbr, within, ncnt, mhb);
    out_gemm_kernel<<<S_SUP / 32, 256, 0, stream>>>(mhb, w2f, b2, ncnt, out);
}